// Round 9
// baseline (158.265 us; speedup 1.0000x reference)
//
#include <hip/hip_runtime.h>
#include <hip/hip_bf16.h>

#define NB 2
#define NS 12
#define NN 800
#define HEADS 8
#define DH 8
#define NBS (NB*NS)        // 24
#define NR (NB*NS*NN)      // 19200 rows

typedef __attribute__((ext_vector_type(4))) float f32x4;
typedef __attribute__((ext_vector_type(4))) short s16x4;
typedef __attribute__((ext_vector_type(8))) short s16x8;

static __device__ __forceinline__ unsigned short f2bf(float f) {
  union { float f; unsigned u; } v; v.f = f;
  unsigned r = (v.u + 0x7FFFu + ((v.u >> 16) & 1u)) >> 16;
  return (unsigned short)r;
}
static __device__ __forceinline__ float bf2f(unsigned short u) {
  union { unsigned u; float f; } v;
  v.u = ((unsigned)u) << 16;
  return v.f;
}
static __device__ __forceinline__ float fexp2(float x) {
  return __builtin_amdgcn_exp2f(x);
}
static __device__ __forceinline__ unsigned cvtpk_bf16(float a, float b) {
  unsigned r;
  asm("v_cvt_pk_bf16_f32 %0, %1, %2" : "=v"(r) : "v"(a), "v"(b));
  return r;
}

#define SC_LOG2 (0.35355339059327373f * 1.44269504088896f)

// ---------------------------------------------------------------------------
// 0) ALL weight conversions in one kernel: 9x 64x64 mats + W1 (64x256) + W2
// ---------------------------------------------------------------------------
__global__ __launch_bounds__(256) void k_wconv(
    const float* __restrict__ w0, const float* __restrict__ w1,
    const float* __restrict__ w2, const float* __restrict__ w3,
    const float* __restrict__ w4, const float* __restrict__ w5,
    const float* __restrict__ w6, const float* __restrict__ w7,
    const float* __restrict__ w8, const float* __restrict__ W1,
    const float* __restrict__ W2, unsigned short* __restrict__ WB,
    unsigned short* __restrict__ W1B, unsigned short* __restrict__ W2B) {
  int i = blockIdx.x * 256 + threadIdx.x;
  if (i < 36864) {
    const float* ws[9] = {w0, w1, w2, w3, w4, w5, w6, w7, w8};
    WB[i] = f2bf(ws[i >> 12][i & 4095]);
  } else if (i < 53248) {
    W1B[i - 36864] = f2bf(W1[i - 36864]);
  } else if (i < 69632) {
    W2B[i - 53248] = f2bf(W2[i - 53248]);
  }
}

// ---------------------------------------------------------------------------
// 1) fused accident-scale + graph linear, TRANSPOSED-PACKED output:
//    HP[bs][c][m] = bf16( (x*sf) @ W_gp + b )[row=(bs,m)][c]
// ---------------------------------------------------------------------------
__global__ __launch_bounds__(256) void k_lin64T(
    const float* __restrict__ x, const unsigned short* __restrict__ Wb,
    const float* __restrict__ bias, unsigned short* __restrict__ HP) {
  __shared__ unsigned short As[32][36];
  __shared__ unsigned short Bs[64][36];
  const int tid = threadIdx.x;
  const int r0 = blockIdx.x * 32;
  const int w = tid >> 6, l = tid & 63;
  const int rb = (w & 1) * 16, cb = (w >> 1) * 32;
  f32x4 acc0 = {0.f, 0.f, 0.f, 0.f}, acc1 = {0.f, 0.f, 0.f, 0.f};
  const int ar = tid >> 3, ak = (tid & 7) * 4;
  const int bc = tid & 63, bm0 = (tid >> 6) * 4;
  const int k4 = (l >> 4) * 4;
  const int arow = rb + (l & 15);
  const int bcol0 = cb + (l & 15);
  const float* xrow = x + (size_t)(r0 + ar) * 64;
  float sf = 1.0f + 0.3f * xrow[62] * __expf(-xrow[63] * (1.0f / 60.0f));
  for (int k0 = 0; k0 < 64; k0 += 32) {
    __syncthreads();
    float4 xv = *(const float4*)(xrow + k0 + ak);
    ushort4 xb;
    xb.x = f2bf(xv.x * sf); xb.y = f2bf(xv.y * sf);
    xb.z = f2bf(xv.z * sf); xb.w = f2bf(xv.w * sf);
    *(ushort4*)&As[ar][ak] = xb;
#pragma unroll
    for (int j = 0; j < 4; ++j) {
      int mp = bm0 + j;
      unsigned lo = Wb[(size_t)(k0 + 2 * mp) * 64 + bc];
      unsigned hi = Wb[(size_t)(k0 + 2 * mp + 1) * 64 + bc];
      *(unsigned*)&Bs[bc][2 * mp] = lo | (hi << 16);
    }
    __syncthreads();
    s16x4 alo = *(const s16x4*)&As[arow][k4];
    s16x4 ahi = *(const s16x4*)&As[arow][k4 + 16];
    s16x8 a = {alo.x, alo.y, alo.z, alo.w, ahi.x, ahi.y, ahi.z, ahi.w};
    s16x4 b0l = *(const s16x4*)&Bs[bcol0][k4];
    s16x4 b0h = *(const s16x4*)&Bs[bcol0][k4 + 16];
    s16x8 bf0 = {b0l.x, b0l.y, b0l.z, b0l.w, b0h.x, b0h.y, b0h.z, b0h.w};
    s16x4 b1l = *(const s16x4*)&Bs[bcol0 + 16][k4];
    s16x4 b1h = *(const s16x4*)&Bs[bcol0 + 16][k4 + 16];
    s16x8 bf1 = {b1l.x, b1l.y, b1l.z, b1l.w, b1h.x, b1h.y, b1h.z, b1h.w};
    acc0 = __builtin_amdgcn_mfma_f32_16x16x32_bf16(a, bf0, acc0, 0, 0, 0);
    acc1 = __builtin_amdgcn_mfma_f32_16x16x32_bf16(a, bf1, acc1, 0, 0, 0);
  }
  const int c0 = cb + (l & 15);
  float b0 = bias[c0], b1 = bias[c0 + 16];
#pragma unroll
  for (int r = 0; r < 4; ++r) {
    int row = r0 + rb + (l >> 4) * 4 + r;
    int bs = row / NN, m = row % NN;
    HP[((size_t)bs * 64 + c0) * NN + m] = f2bf(acc0[r] + b0);
    HP[((size_t)bs * 64 + c0 + 16) * NN + m] = f2bf(acc1[r] + b1);
  }
}

// ---------------------------------------------------------------------------
// 2) MFMA graph propagation: 32-node x 64-ch tile, HP-layout input (b128),
//    adj read as f32 + converted inline. Grid NBS*25.
// ---------------------------------------------------------------------------
template <bool LAST>
__global__ __launch_bounds__(256) void k_prop_mfma(
    const float* __restrict__ adj,
    const unsigned short* __restrict__ HPin,
    const float* __restrict__ x,
    unsigned short* __restrict__ HPout,
    float* __restrict__ pout,
    unsigned short* __restrict__ pbout) {
  __shared__ unsigned short As[32][36];
  __shared__ unsigned short Bs[64][40];
  const int tid = threadIdx.x;
  const int bid = blockIdx.x;
  const int bs = bid / 25, mt = bid % 25;
  const int b = bs / NS;
  const int n0 = mt * 32;
  const float* abase = adj + (size_t)b * NN * NN + (size_t)n0 * NN;
  const unsigned short* hbase = HPin + (size_t)bs * 64 * NN;
  const int w = tid >> 6, l = tid & 63;
  const int rb = (w & 1) * 16;
  const int cb = (w >> 1) * 32;
  f32x4 acc0 = {0.f, 0.f, 0.f, 0.f}, acc1 = {0.f, 0.f, 0.f, 0.f};
  const int ar = tid >> 3, ak = (tid & 7) * 4;
  const int bc = tid & 63, bq = tid >> 6;
  const int k4 = (l >> 4) * 4;
  const int arow = rb + (l & 15);
  const int bcol0 = cb + (l & 15);
  for (int m0 = 0; m0 < NN; m0 += 32) {
    __syncthreads();
    float4 av = *(const float4*)(abase + (size_t)ar * NN + m0 + ak);
    ushort4 ab;
    ab.x = f2bf(av.x); ab.y = f2bf(av.y);
    ab.z = f2bf(av.z); ab.w = f2bf(av.w);
    *(ushort4*)&As[ar][ak] = ab;
    *(s16x8*)&Bs[bc][bq * 8] =
        *(const s16x8*)(hbase + (size_t)bc * NN + m0 + bq * 8);
    __syncthreads();
    s16x4 alo = *(const s16x4*)&As[arow][k4];
    s16x4 ahi = *(const s16x4*)&As[arow][k4 + 16];
    s16x8 a = {alo.x, alo.y, alo.z, alo.w, ahi.x, ahi.y, ahi.z, ahi.w};
    s16x4 b0l = *(const s16x4*)&Bs[bcol0][k4];
    s16x4 b0h = *(const s16x4*)&Bs[bcol0][k4 + 16];
    s16x8 bf0 = {b0l.x, b0l.y, b0l.z, b0l.w, b0h.x, b0h.y, b0h.z, b0h.w};
    s16x4 b1l = *(const s16x4*)&Bs[bcol0 + 16][k4];
    s16x4 b1h = *(const s16x4*)&Bs[bcol0 + 16][k4 + 16];
    s16x8 bf1 = {b1l.x, b1l.y, b1l.z, b1l.w, b1h.x, b1h.y, b1h.z, b1h.w};
    acc0 = __builtin_amdgcn_mfma_f32_16x16x32_bf16(a, bf0, acc0, 0, 0, 0);
    acc1 = __builtin_amdgcn_mfma_f32_16x16x32_bf16(a, bf1, acc1, 0, 0, 0);
  }
  const int c0 = cb + (l & 15);
  if (LAST) {
#pragma unroll
    for (int r = 0; r < 4; ++r) {
      int n = n0 + rb + (l >> 4) * 4 + r;
      float v0 = fmaxf(acc0[r], 0.f);
      float v1 = fmaxf(acc1[r], 0.f);
      size_t i0 = ((size_t)bs * NN + n) * 64 + c0;
      size_t i1 = i0 + 16;
      float p0 = v0 + x[i0], p1 = v1 + x[i1];
      pout[i0] = p0;
      pout[i1] = p1;
      pbout[i0] = f2bf(p0);
      pbout[i1] = f2bf(p1);
    }
  } else {
    int nb = n0 + rb + (l >> 4) * 4;
    s16x4 o0, o1;
#pragma unroll
    for (int r = 0; r < 4; ++r) {
      o0[r] = (short)f2bf(fmaxf(acc0[r], 0.f));
      o1[r] = (short)f2bf(fmaxf(acc1[r], 0.f));
    }
    *(s16x4*)&HPout[((size_t)bs * 64 + c0) * NN + nb] = o0;
    *(s16x4*)&HPout[((size_t)bs * 64 + c0 + 16) * NN + nb] = o1;
  }
}

// ---------------------------------------------------------------------------
// 3) MFMA fused QKV (bf16 out); Q scaled by qscale
// ---------------------------------------------------------------------------
__global__ __launch_bounds__(256) void k_qkv_mfma(
    const unsigned short* __restrict__ Xb,
    const unsigned short* __restrict__ Wq,
    const unsigned short* __restrict__ Wk,
    const unsigned short* __restrict__ Wv,
    const float* __restrict__ bq, const float* __restrict__ bk,
    const float* __restrict__ bv, float qscale,
    unsigned short* __restrict__ Qo, unsigned short* __restrict__ Ko,
    unsigned short* __restrict__ Vo) {
  __shared__ unsigned short As[32][36];
  __shared__ unsigned short Bs[3][64][36];
  const int tid = threadIdx.x;
  const int r0 = blockIdx.x * 32;
  const int w = tid >> 6, l = tid & 63;
  const int rb = (w & 1) * 16;
  const int cb = (w >> 1) * 32;
  f32x4 acc[3][2];
#pragma unroll
  for (int i = 0; i < 3; ++i)
#pragma unroll
    for (int j = 0; j < 2; ++j) acc[i][j] = (f32x4){0.f, 0.f, 0.f, 0.f};
  const unsigned short* Wm[3] = {Wq, Wk, Wv};
  const int ar = tid >> 3, ak = (tid & 7) * 4;
  const int bc = tid & 63, bm0 = (tid >> 6) * 4;
  const int k4 = (l >> 4) * 4;
  const int arow = rb + (l & 15);
  const int bcol0 = cb + (l & 15);
  for (int k0 = 0; k0 < 64; k0 += 32) {
    __syncthreads();
    *(s16x4*)&As[ar][ak] =
        *(const s16x4*)(Xb + (size_t)(r0 + ar) * 64 + k0 + ak);
#pragma unroll
    for (int wm = 0; wm < 3; ++wm) {
#pragma unroll
      for (int j = 0; j < 4; ++j) {
        int mp = bm0 + j;
        unsigned lo = Wm[wm][(size_t)(k0 + 2 * mp) * 64 + bc];
        unsigned hi = Wm[wm][(size_t)(k0 + 2 * mp + 1) * 64 + bc];
        *(unsigned*)&Bs[wm][bc][2 * mp] = lo | (hi << 16);
      }
    }
    __syncthreads();
    s16x4 alo = *(const s16x4*)&As[arow][k4];
    s16x4 ahi = *(const s16x4*)&As[arow][k4 + 16];
    s16x8 a = {alo.x, alo.y, alo.z, alo.w, ahi.x, ahi.y, ahi.z, ahi.w};
#pragma unroll
    for (int wm = 0; wm < 3; ++wm) {
      s16x4 b0l = *(const s16x4*)&Bs[wm][bcol0][k4];
      s16x4 b0h = *(const s16x4*)&Bs[wm][bcol0][k4 + 16];
      s16x8 bf0 = {b0l.x, b0l.y, b0l.z, b0l.w, b0h.x, b0h.y, b0h.z, b0h.w};
      s16x4 b1l = *(const s16x4*)&Bs[wm][bcol0 + 16][k4];
      s16x4 b1h = *(const s16x4*)&Bs[wm][bcol0 + 16][k4 + 16];
      s16x8 bf1 = {b1l.x, b1l.y, b1l.z, b1l.w, b1h.x, b1h.y, b1h.z, b1h.w};
      acc[wm][0] = __builtin_amdgcn_mfma_f32_16x16x32_bf16(a, bf0, acc[wm][0], 0, 0, 0);
      acc[wm][1] = __builtin_amdgcn_mfma_f32_16x16x32_bf16(a, bf1, acc[wm][1], 0, 0, 0);
    }
  }
  const float* bm[3] = {bq, bk, bv};
  unsigned short* Om[3] = {Qo, Ko, Vo};
  const int c0 = cb + (l & 15);
#pragma unroll
  for (int wm = 0; wm < 3; ++wm) {
    float b0 = bm[wm][c0], b1 = bm[wm][c0 + 16];
    float sc = (wm == 0) ? qscale : 1.0f;
#pragma unroll
    for (int r = 0; r < 4; ++r) {
      int row = r0 + rb + (l >> 4) * 4 + r;
      Om[wm][(size_t)row * 64 + c0] = f2bf((acc[wm][0][r] + b0) * sc);
      Om[wm][(size_t)row * 64 + c0 + 16] = f2bf((acc[wm][1][r] + b1) * sc);
    }
  }
}

// ---------------------------------------------------------------------------
// 4) spatial attention v4: swapped QK^T + MFMA PV, fixed softmax max (m=0),
//    ones-row denominator.
// ---------------------------------------------------------------------------
__global__ __launch_bounds__(256) void k_sattn4(
    const unsigned short* __restrict__ Qb,
    const unsigned short* __restrict__ Kb,
    const unsigned short* __restrict__ Vb,
    unsigned short* __restrict__ OB) {
  __shared__ unsigned short Ks[800][8];
  __shared__ unsigned short Vt[25 * 256 + 256];  // pad for masked OOB reads
  const int bs = blockIdx.x, h = blockIdx.y;
  const int tid = threadIdx.x;
  const size_t base = (size_t)bs * NN * 64 + h * DH;
  for (int r = tid; r < NN; r += 256)
    *(s16x8*)&Ks[r][0] = *(const s16x8*)(Kb + base + (size_t)r * 64);
  if (tid < 200) {
    int t = tid >> 3, c = tid & 7;
    int r = t * 32 + c * 4;
    s16x8 v0 = *(const s16x8*)(Vb + base + (size_t)r * 64);
    s16x8 v1 = *(const s16x8*)(Vb + base + (size_t)(r + 1) * 64);
    s16x8 v2 = *(const s16x8*)(Vb + base + (size_t)(r + 2) * 64);
    s16x8 v3 = *(const s16x8*)(Vb + base + (size_t)(r + 3) * 64);
#pragma unroll
    for (int d = 0; d < 8; ++d) {
      unsigned lo = (unsigned short)v0[d] | ((unsigned)(unsigned short)v1[d] << 16);
      unsigned hi = (unsigned short)v2[d] | ((unsigned)(unsigned short)v3[d] << 16);
      unsigned* dst = (unsigned*)&Vt[t * 256 + d * 32 + ((c ^ d) & 7) * 4];
      dst[0] = lo;
      dst[1] = hi;
    }
  }
  __syncthreads();
  const int w = tid >> 6, l = tid & 63;
  const int q0 = blockIdx.z * 128 + w * 32;
  if (q0 >= NN) return;
  const int r15 = l & 15, g = l >> 4;
  const int dd = r15;
  const int off1 = dd * 32 + ((g ^ dd) & 7) * 4;
  const int off2 = dd * 32 + (((4 + g) ^ dd) & 7) * 4;
  s16x4 qvA = *(const s16x4*)(Qb + base + (size_t)(q0 + r15) * 64 + (g & 1) * 4);
  s16x4 qvB = *(const s16x4*)(Qb + base + (size_t)(q0 + 16 + r15) * 64 + (g & 1) * 4);
  s16x8 qfA = {0, 0, 0, 0, 0, 0, 0, 0};
  s16x8 qfB = {0, 0, 0, 0, 0, 0, 0, 0};
  if (g < 2) {
    qfA[0] = qvA.x; qfA[1] = qvA.y; qfA[2] = qvA.z; qfA[3] = qvA.w;
    qfB[0] = qvB.x; qfB[1] = qvB.y; qfB[2] = qvB.z; qfB[3] = qvB.w;
  }
  const short one_bf = (short)0x3F80;
  f32x4 accA = {0.f, 0.f, 0.f, 0.f}, accB = {0.f, 0.f, 0.f, 0.f};
  const f32x4 zero4 = {0.f, 0.f, 0.f, 0.f};
  for (int t = 0; t < 25; ++t) {
    s16x4 ka = *(const s16x4*)&Ks[t * 32 + r15][(g & 1) * 4];
    s16x4 kb = *(const s16x4*)&Ks[t * 32 + 16 + r15][(g & 1) * 4];
    s16x8 kfa = {0, 0, 0, 0, 0, 0, 0, 0};
    s16x8 kfb = {0, 0, 0, 0, 0, 0, 0, 0};
    if (g < 2) {
      kfa[0] = ka.x; kfa[1] = ka.y; kfa[2] = ka.z; kfa[3] = ka.w;
      kfb[0] = kb.x; kfb[1] = kb.y; kfb[2] = kb.z; kfb[3] = kb.w;
    }
    s16x4 va = *(const s16x4*)&Vt[t * 256 + off1];
    s16x4 vb = *(const s16x4*)&Vt[t * 256 + off2];
    s16x8 vf;
    if (dd < 8) {
      vf = (s16x8){va.x, va.y, va.z, va.w, vb.x, vb.y, vb.z, vb.w};
    } else if (dd == 8) {
      vf = (s16x8){one_bf, one_bf, one_bf, one_bf, one_bf, one_bf, one_bf, one_bf};
    } else {
      vf = (s16x8){0, 0, 0, 0, 0, 0, 0, 0};
    }
    f32x4 sA1 = __builtin_amdgcn_mfma_f32_16x16x32_bf16(kfa, qfA, zero4, 0, 0, 0);
    f32x4 sA2 = __builtin_amdgcn_mfma_f32_16x16x32_bf16(kfb, qfA, zero4, 0, 0, 0);
    f32x4 sB1 = __builtin_amdgcn_mfma_f32_16x16x32_bf16(kfa, qfB, zero4, 0, 0, 0);
    f32x4 sB2 = __builtin_amdgcn_mfma_f32_16x16x32_bf16(kfb, qfB, zero4, 0, 0, 0);
    float pA[8], pB[8];
#pragma unroll
    for (int r = 0; r < 4; ++r) {
      pA[r] = fexp2(sA1[r]);
      pA[4 + r] = fexp2(sA2[r]);
      pB[r] = fexp2(sB1[r]);
      pB[4 + r] = fexp2(sB2[r]);
    }
    union { unsigned u[4]; s16x8 v; } puA, puB;
    puA.u[0] = cvtpk_bf16(pA[0], pA[1]);
    puA.u[1] = cvtpk_bf16(pA[2], pA[3]);
    puA.u[2] = cvtpk_bf16(pA[4], pA[5]);
    puA.u[3] = cvtpk_bf16(pA[6], pA[7]);
    puB.u[0] = cvtpk_bf16(pB[0], pB[1]);
    puB.u[1] = cvtpk_bf16(pB[2], pB[3]);
    puB.u[2] = cvtpk_bf16(pB[4], pB[5]);
    puB.u[3] = cvtpk_bf16(pB[6], pB[7]);
    accA = __builtin_amdgcn_mfma_f32_16x16x32_bf16(vf, puA.v, accA, 0, 0, 0);
    accB = __builtin_amdgcn_mfma_f32_16x16x32_bf16(vf, puB.v, accB, 0, 0, 0);
  }
  float lsA = __shfl(accA[0], 32 + r15, 64);
  float lsB = __shfl(accB[0], 32 + r15, 64);
  float invA = 1.f / lsA;
  float invB = 1.f / lsB;
  if (g < 2) {
#pragma unroll
    for (int r = 0; r < 4; ++r) {
      int d = g * 4 + r;
      OB[base + (size_t)(q0 + r15) * 64 + d] = f2bf(accA[r] * invA);
      OB[base + (size_t)(q0 + 16 + r15) * 64 + d] = f2bf(accB[r] * invB);
    }
  }
}

// ---------------------------------------------------------------------------
// 5) MFMA proj + residual + LN (K=64).
//    LN2=false: bfout = bf16 copy of LN output.
//    LN2=true:  bfout = bf16( LN(LN_output; g2, be2) )  (fused second LN)
// ---------------------------------------------------------------------------
template <bool LN2>
__global__ __launch_bounds__(256) void k_projln_mfma(
    const unsigned short* __restrict__ Xb,
    const unsigned short* __restrict__ Wb,
    const float* __restrict__ bias, const float* __restrict__ res,
    const float* __restrict__ g, const float* __restrict__ be,
    const float* __restrict__ g2, const float* __restrict__ be2,
    float* __restrict__ out, unsigned short* __restrict__ bfout) {
  __shared__ unsigned short As[32][36];
  __shared__ unsigned short Bs[64][36];
  __shared__ float CT[32][68];
  const int tid = threadIdx.x;
  const int r0 = blockIdx.x * 32;
  const int w = tid >> 6, l = tid & 63;
  const int rb = (w & 1) * 16, cb = (w >> 1) * 32;
  f32x4 acc0 = {0.f, 0.f, 0.f, 0.f}, acc1 = {0.f, 0.f, 0.f, 0.f};
  const int ar = tid >> 3, ak = (tid & 7) * 4;
  const int bc = tid & 63, bm0 = (tid >> 6) * 4;
  const int k4 = (l >> 4) * 4;
  const int arow = rb + (l & 15);
  const int bcol0 = cb + (l & 15);
  for (int k0 = 0; k0 < 64; k0 += 32) {
    __syncthreads();
    *(s16x4*)&As[ar][ak] = *(const s16x4*)(Xb + (size_t)(r0 + ar) * 64 + k0 + ak);
#pragma unroll
    for (int j = 0; j < 4; ++j) {
      int mp = bm0 + j;
      unsigned lo = Wb[(size_t)(k0 + 2 * mp) * 64 + bc];
      unsigned hi = Wb[(size_t)(k0 + 2 * mp + 1) * 64 + bc];
      *(unsigned*)&Bs[bc][2 * mp] = lo | (hi << 16);
    }
    __syncthreads();
    s16x4 alo = *(const s16x4*)&As[arow][k4];
    s16x4 ahi = *(const s16x4*)&As[arow][k4 + 16];
    s16x8 a = {alo.x, alo.y, alo.z, alo.w, ahi.x, ahi.y, ahi.z, ahi.w};
    s16x4 b0l = *(const s16x4*)&Bs[bcol0][k4];
    s16x4 b0h = *(const s16x4*)&Bs[bcol0][k4 + 16];
    s16x8 bf0 = {b0l.x, b0l.y, b0l.z, b0l.w, b0h.x, b0h.y, b0h.z, b0h.w};
    s16x4 b1l = *(const s16x4*)&Bs[bcol0 + 16][k4];
    s16x4 b1h = *(const s16x4*)&Bs[bcol0 + 16][k4 + 16];
    s16x8 bf1 = {b1l.x, b1l.y, b1l.z, b1l.w, b1h.x, b1h.y, b1h.z, b1h.w};
    acc0 = __builtin_amdgcn_mfma_f32_16x16x32_bf16(a, bf0, acc0, 0, 0, 0);
    acc1 = __builtin_amdgcn_mfma_f32_16x16x32_bf16(a, bf1, acc1, 0, 0, 0);
  }
  const int c0 = cb + (l & 15);
#pragma unroll
  for (int r = 0; r < 4; ++r) {
    int row = rb + (l >> 4) * 4 + r;
    size_t gi = (size_t)(r0 + row) * 64;
    CT[row][c0] = acc0[r] + bias[c0] + res[gi + c0];
    CT[row][c0 + 16] = acc1[r] + bias[c0 + 16] + res[gi + c0 + 16];
  }
  __syncthreads();
  const int row = tid >> 3, sub = tid & 7;
  float v[8];
#pragma unroll
  for (int i = 0; i < 8; ++i) v[i] = CT[row][sub * 8 + i];
  float s = 0.f;
#pragma unroll
  for (int i = 0; i < 8; ++i) s += v[i];
#pragma unroll
  for (int off = 1; off < 8; off <<= 1) s += __shfl_xor(s, off, 64);
  float mean = s * (1.f / 64.f);
  float q = 0.f;
#pragma unroll
  for (int i = 0; i < 8; ++i) {
    float ddd = v[i] - mean;
    q += ddd * ddd;
  }
#pragma unroll
  for (int off = 1; off < 8; off <<= 1) q += __shfl_xor(q, off, 64);
  float rstd = rsqrtf(q * (1.f / 64.f) + 1e-5f);
  float r4[8];
#pragma unroll
  for (int i = 0; i < 8; ++i)
    r4[i] = (v[i] - mean) * rstd * g[sub * 8 + i] + be[sub * 8 + i];
  float* op = out + (size_t)(r0 + row) * 64 + sub * 8;
  *(float4*)op = (float4){r4[0], r4[1], r4[2], r4[3]};
  *(float4*)(op + 4) = (float4){r4[4], r4[5], r4[6], r4[7]};
  unsigned short* bp = bfout + (size_t)(r0 + row) * 64 + sub * 8;
  if (!LN2) {
#pragma unroll
    for (int i = 0; i < 8; ++i) bp[i] = f2bf(r4[i]);
  } else {
    float s2 = 0.f;
#pragma unroll
    for (int i = 0; i < 8; ++i) s2 += r4[i];
#pragma unroll
    for (int off = 1; off < 8; off <<= 1) s2 += __shfl_xor(s2, off, 64);
    float mean2 = s2 * (1.f / 64.f);
    float q2 = 0.f;
#pragma unroll
    for (int i = 0; i < 8; ++i) {
      float d2 = r4[i] - mean2;
      q2 += d2 * d2;
    }
#pragma unroll
    for (int off = 1; off < 8; off <<= 1) q2 += __shfl_xor(q2, off, 64);
    float rstd2 = rsqrtf(q2 * (1.f / 64.f) + 1e-5f);
#pragma unroll
    for (int i = 0; i < 8; ++i)
      bp[i] = f2bf((r4[i] - mean2) * rstd2 * g2[sub * 8 + i] + be2[sub * 8 + i]);
  }
}

// ---------------------------------------------------------------------------
// 6) temporal attention: one block per (b,n), L = 12; bf16 in/out
// ---------------------------------------------------------------------------
__global__ __launch_bounds__(256) void k_tattn(
    const unsigned short* __restrict__ Q, const unsigned short* __restrict__ K,
    const unsigned short* __restrict__ V, unsigned short* __restrict__ O) {
  int b = blockIdx.x / NN, n = blockIdx.x % NN;
  __shared__ float Qs[12][64], Ks[12][64], Vs[12][64];
  int tid = threadIdx.x;
  for (int i = tid; i < 12 * 64; i += 256) {
    int s = i >> 6, c = i & 63;
    size_t idx = (((size_t)b * NS + s) * NN + n) * 64 + c;
    Qs[s][c] = bf2f(Q[idx]);
    Ks[s][c] = bf2f(K[idx]);
    Vs[s][c] = bf2f(V[idx]);
  }
  __syncthreads();
  for (int wi = tid; wi < 12 * 64; wi += 256) {
    int l = wi >> 6, c = wi & 63;
    int h8 = c & 56;
    float sc[12];
    float mx = -1e30f;
#pragma unroll
    for (int m = 0; m < 12; ++m) {
      float s = 0.f;
#pragma unroll
      for (int d = 0; d < 8; ++d) s += Qs[l][h8 + d] * Ks[m][h8 + d];
      s *= 0.35355339059327373f;
      sc[m] = s;
      mx = fmaxf(mx, s);
    }
    float sum = 0.f;
#pragma unroll
    for (int m = 0; m < 12; ++m) {
      sc[m] = __expf(sc[m] - mx);
      sum += sc[m];
    }
    float inv = 1.f / sum;
    float o = 0.f;
#pragma unroll
    for (int m = 0; m < 12; ++m) o += sc[m] * Vs[m][c];
    size_t idx = (((size_t)b * NS + l) * NN + n) * 64 + c;
    O[idx] = f2bf(o * inv);
  }
}

// ---------------------------------------------------------------------------
// 7) Fused FFN: out = LN( relu(Xb@W1+b1)@W2 + b2 + res ; g, be )
//    Block: 32 rows. hid tile (32x256 bf16) lives in LDS.
// ---------------------------------------------------------------------------
__global__ __launch_bounds__(256) void k_ffn_fused(
    const unsigned short* __restrict__ Xb,   // [NR][64] bf16 (LN1 output)
    const unsigned short* __restrict__ W1b,  // [64][256] bf16
    const float* __restrict__ b1,
    const unsigned short* __restrict__ W2b,  // [256][64] bf16
    const float* __restrict__ b2,
    const float* __restrict__ res,           // [NR][64] f32 (attn_out)
    const float* __restrict__ g, const float* __restrict__ be,
    float* __restrict__ out) {
  __shared__ unsigned short As[32][68];
  __shared__ unsigned short Bs[64][66];
  __shared__ unsigned short Hs[32][264];
  __shared__ float CT[32][68];
  const int tid = threadIdx.x;
  const int r0 = blockIdx.x * 32;
  const int w = tid >> 6, l = tid & 63;
  const int rb = (w & 1) * 16, cb = (w >> 1) * 32;
  const int r15 = l & 15;
  const int k4 = (l >> 4) * 4;
  const int arow = rb + r15;
  const int bcol0 = cb + r15;
  // stage X (K=64) once
  {
    int ar = tid >> 3, ak8 = (tid & 7) * 8;
    *(s16x8*)&As[ar][ak8] = *(const s16x8*)(Xb + (size_t)(r0 + ar) * 64 + ak8);
  }
  const int sbc = tid & 63;
  // ---- phase 1: hid = relu(X @ W1 + b1), 4 column chunks of 64 ----
  for (int c = 0; c < 4; ++c) {
    __syncthreads();
    {
      const int smp0 = (tid >> 6) * 8;
      int gcol = c * 64 + sbc;
#pragma unroll
      for (int j = 0; j < 8; ++j) {
        int mp = smp0 + j;
        unsigned lo = W1b[(size_t)(2 * mp) * 256 + gcol];
        unsigned hi = W1b[(size_t)(2 * mp + 1) * 256 + gcol];
        *(unsigned*)&Bs[sbc][2 * mp] = lo | (hi << 16);
      }
    }
    __syncthreads();
    f32x4 acc0 = {0.f, 0.f, 0.f, 0.f}, acc1 = {0.f, 0.f, 0.f, 0.f};
#pragma unroll
    for (int k0 = 0; k0 < 64; k0 += 32) {
      s16x4 alo = *(const s16x4*)&As[arow][k0 + k4];
      s16x4 ahi = *(const s16x4*)&As[arow][k0 + k4 + 16];
      s16x8 a = {alo.x, alo.y, alo.z, alo.w, ahi.x, ahi.y, ahi.z, ahi.w};
      s16x4 b0l = *(const s16x4*)&Bs[bcol0][k0 + k4];
      s16x4 b0h = *(const s16x4*)&Bs[bcol0][k0 + k4 + 16];
      s16x8 bf0 = {b0l.x, b0l.y, b0l.z, b0l.w, b0h.x, b0h.y, b0h.z, b0h.w};
      s16x4 b1l = *(const s16x4*)&Bs[bcol0 + 16][k0 + k4];
      s16x4 b1h = *(const s16x4*)&Bs[bcol0 + 16][k0 + k4 + 16];
      s16x8 bf1 = {b1l.x, b1l.y, b1l.z, b1l.w, b1h.x, b1h.y, b1h.z, b1h.w};
      acc0 = __builtin_amdgcn_mfma_f32_16x16x32_bf16(a, bf0, acc0, 0, 0, 0);
      acc1 = __builtin_amdgcn_mfma_f32_16x16x32_bf16(a, bf1, acc1, 0, 0, 0);
    }
    int c0 = cb + r15;
    float bb0 = b1[c * 64 + c0], bb1v = b1[c * 64 + c0 + 16];
#pragma unroll
    for (int r = 0; r < 4; ++r) {
      int row = rb + (l >> 4) * 4 + r;
      Hs[row][c * 64 + c0] = f2bf(fmaxf(acc0[r] + bb0, 0.f));
      Hs[row][c * 64 + c0 + 16] = f2bf(fmaxf(acc1[r] + bb1v, 0.f));
    }
  }
  // ---- phase 2: out = Hs @ W2 + b2 + res ----
  f32x4 acc0 = {0.f, 0.f, 0.f, 0.f}, acc1 = {0.f, 0.f, 0.f, 0.f};
  const int smp4 = (tid >> 6) * 4;
  for (int k0 = 0; k0 < 256; k0 += 32) {
    __syncthreads();
#pragma unroll
    for (int j = 0; j < 4; ++j) {
      int mp = smp4 + j;
      unsigned lo = W2b[(size_t)(k0 + 2 * mp) * 64 + sbc];
      unsigned hi = W2b[(size_t)(k0 + 2 * mp + 1) * 64 + sbc];
      *(unsigned*)&Bs[sbc][2 * mp] = lo | (hi << 16);
    }
    __syncthreads();
    s16x4 alo = *(const s16x4*)&Hs[arow][k0 + k4];
    s16x4 ahi = *(const s16x4*)&Hs[arow][k0 + k4 + 16];
    s16x8 a = {alo.x, alo.y, alo.z, alo.w, ahi.x, ahi.y, ahi.z, ahi.w};
    s16x4 b0l = *(const s16x4*)&Bs[bcol0][k4];
    s16x4 b0h = *(const s16x4*)&Bs[bcol0][k4 + 16];
    s16x8 bf0 = {b0l.x, b0l.y, b0l.z, b0l.w, b0h.x, b0h.y, b0h.z, b0h.w};
    s16x4 b1l = *(const s16x4*)&Bs[bcol0 + 16][k4];
    s16x4 b1h = *(const s16x4*)&Bs[bcol0 + 16][k4 + 16];
    s16x8 bf1 = {b1l.x, b1l.y, b1l.z, b1l.w, b1h.x, b1h.y, b1h.z, b1h.w};
    acc0 = __builtin_amdgcn_mfma_f32_16x16x32_bf16(a, bf0, acc0, 0, 0, 0);
    acc1 = __builtin_amdgcn_mfma_f32_16x16x32_bf16(a, bf1, acc1, 0, 0, 0);
  }
  const int c0 = cb + r15;
#pragma unroll
  for (int r = 0; r < 4; ++r) {
    int row = rb + (l >> 4) * 4 + r;
    size_t gi = (size_t)(r0 + row) * 64;
    CT[row][c0] = acc0[r] + b2[c0] + res[gi + c0];
    CT[row][c0 + 16] = acc1[r] + b2[c0 + 16] + res[gi + c0 + 16];
  }
  __syncthreads();
  const int row = tid >> 3, sub = tid & 7;
  float v[8];
#pragma unroll
  for (int i = 0; i < 8; ++i) v[i] = CT[row][sub * 8 + i];
  float s = 0.f;
#pragma unroll
  for (int i = 0; i < 8; ++i) s += v[i];
#pragma unroll
  for (int off = 1; off < 8; off <<= 1) s += __shfl_xor(s, off, 64);
  float mean = s * (1.f / 64.f);
  float q = 0.f;
#pragma unroll
  for (int i = 0; i < 8; ++i) {
    float d = v[i] - mean;
    q += d * d;
  }
#pragma unroll
  for (int off = 1; off < 8; off <<= 1) q += __shfl_xor(q, off, 64);
  float rstd = rsqrtf(q * (1.f / 64.f) + 1e-5f);
  float r4[8];
#pragma unroll
  for (int i = 0; i < 8; ++i)
    r4[i] = (v[i] - mean) * rstd * g[sub * 8 + i] + be[sub * 8 + i];
  float* op = out + (size_t)(r0 + row) * 64 + sub * 8;
  *(float4*)op = (float4){r4[0], r4[1], r4[2], r4[3]};
  *(float4*)(op + 4) = (float4){r4[4], r4[5], r4[6], r4[7]};
}

// ---------------------------------------------------------------------------
extern "C" void kernel_launch(void* const* d_in, const int* in_sizes, int n_in,
                              void* d_out, int out_size, void* d_ws,
                              size_t ws_size, hipStream_t stream) {
  const float* x = (const float*)d_in[0];
  const float* adj = (const float*)d_in[1];
  const float* W_gp = (const float*)d_in[2];
  const float* b_gp = (const float*)d_in[3];
  const float* Wq_s = (const float*)d_in[4];
  const float* Wk_s = (const float*)d_in[5];
  const float* Wv_s = (const float*)d_in[6];
  const float* Wo_s = (const float*)d_in[7];
  const float* bq_s = (const float*)d_in[8];
  const float* bk_s = (const float*)d_in[9];
  const float* bv_s = (const float*)d_in[10];
  const float* bo_s = (const float*)d_in[11];
  const float* g_s = (const float*)d_in[12];
  const float* be_s = (const float*)d_in[13];
  const float* Wq_t = (const float*)d_in[14];
  const float* Wk_t = (const float*)d_in[15];
  const float* Wv_t = (const float*)d_in[16];
  const float* Wo_t = (const float*)d_in[17];
  const float* bq_t = (const float*)d_in[18];
  const float* bk_t = (const float*)d_in[19];
  const float* bv_t = (const float*)d_in[20];
  const float* bo_t = (const float*)d_in[21];
  const float* g_t = (const float*)d_in[22];
  const float* be_t = (const float*)d_in[23];
  const float* W1 = (const float*)d_in[24];
  const float* b1 = (const float*)d_in[25];
  const float* W2 = (const float*)d_in[26];
  const float* b2 = (const float*)d_in[27];
  const float* g1 = (const float*)d_in[28];
  const float* be1 = (const float*)d_in[29];
  const float* g2 = (const float*)d_in[30];
  const float* be2 = (const float*)d_in[31];
  float* out = (float*)d_out;

  float* ws = (float*)d_ws;
  const size_t U = (size_t)NR * 64;  // 1,228,800 floats
  float* A = ws + 0 * U;
  float* Bb = ws + 1 * U;
  float* C = ws + 2 * U;
  float* D = ws + 3 * U;
  float* P = ws + 4 * U;
  // bf16 overlays
  unsigned short* QB = (unsigned short*)A;    // spatial Q
  unsigned short* KB = (unsigned short*)Bb;   // spatial K
  unsigned short* VB = (unsigned short*)C;    // spatial V
  unsigned short* OBuf = (unsigned short*)D;  // sattn out
  unsigned short* Q2 = (unsigned short*)C;    // temporal Q (spatial done)
  unsigned short* K2 = (unsigned short*)D;
  unsigned short* V2 = (unsigned short*)(ws + 5 * U + U);  // after PB region
  unsigned short* PB = (unsigned short*)(ws + 5 * U);
  unsigned short* LNB = (unsigned short*)(ws + 7 * U);  // also TB
  unsigned short* TB = LNB;
  unsigned short* W1B = (unsigned short*)(ws + 7 * U + U / 2);
  unsigned short* W2B = W1B + 16384;
  unsigned short* HP0 = (unsigned short*)(ws + 9 * U);
  unsigned short* HP1 = (unsigned short*)(ws + 9 * U + U / 2);
  unsigned short* WB = (unsigned short*)(ws + 10 * U + 650240);  // 9*4096 sh

  dim3 blk(256);
  // 0) all weight conversions (one launch)
  k_wconv<<<272, blk, 0, stream>>>(Wq_s, Wk_s, Wv_s, Wq_t, Wk_t, Wv_t, W_gp,
                                   Wo_s, Wo_t, W1, W2, WB, W1B, W2B);
  // 1) fused accident-scale + graph linear -> HP0 (transposed-packed bf16)
  k_lin64T<<<NR / 32, blk, 0, stream>>>(x, WB + 6 * 4096, b_gp, HP0);
  // 2) 3 MFMA propagation steps (adj converted inline)
  k_prop_mfma<false><<<NBS * 25, blk, 0, stream>>>(adj, HP0, x, HP1, P, PB);
  k_prop_mfma<false><<<NBS * 25, blk, 0, stream>>>(adj, HP1, x, HP0, P, PB);
  k_prop_mfma<true><<<NBS * 25, blk, 0, stream>>>(adj, HP0, x, HP1, P, PB);
  // 3) spatial: QKV (Q pre-scaled) -> sattn4 -> proj+LN -> A (f32) + PB
  k_qkv_mfma<<<NR / 32, blk, 0, stream>>>(PB, WB, WB + 4096, WB + 8192, bq_s,
                                          bk_s, bv_s, SC_LOG2, QB, KB, VB);
  k_sattn4<<<dim3(NBS, HEADS, 7), blk, 0, stream>>>(QB, KB, VB, OBuf);
  k_projln_mfma<false><<<NR / 32, blk, 0, stream>>>(
      OBuf, WB + 7 * 4096, bo_s, P, g_s, be_s, nullptr, nullptr, A, PB);
  // 4) temporal: QKV -> tattn -> proj+LN_t (+fused LN1) -> Bb (f32) + LNB
  k_qkv_mfma<<<NR / 32, blk, 0, stream>>>(PB, WB + 12288, WB + 16384,
                                          WB + 20480, bq_t, bk_t, bv_t, 1.0f,
                                          Q2, K2, V2);
  k_tattn<<<NB * NN, blk, 0, stream>>>(Q2, K2, V2, TB);
  k_projln_mfma<true><<<NR / 32, blk, 0, stream>>>(
      TB, WB + 8 * 4096, bo_t, A, g_t, be_t, g1, be1, Bb, LNB);
  // 5) fused FFN (ffn1 + ffn2 + residual + final LN) -> out
  k_ffn_fused<<<NR / 32, blk, 0, stream>>>(LNB, W1B, b1, W2B, b2, Bb, g2, be2,
                                           out);
}

// Round 10
// 150.717 us; speedup vs baseline: 1.0501x; 1.0501x over previous
//
#include <hip/hip_runtime.h>
#include <hip/hip_bf16.h>

#define NB 2
#define NS 12
#define NN 800
#define HEADS 8
#define DH 8
#define NBS (NB*NS)        // 24
#define NR (NB*NS*NN)      // 19200 rows

typedef __attribute__((ext_vector_type(4))) float f32x4;
typedef __attribute__((ext_vector_type(4))) short s16x4;
typedef __attribute__((ext_vector_type(8))) short s16x8;

static __device__ __forceinline__ unsigned short f2bf(float f) {
  union { float f; unsigned u; } v; v.f = f;
  unsigned r = (v.u + 0x7FFFu + ((v.u >> 16) & 1u)) >> 16;
  return (unsigned short)r;
}
static __device__ __forceinline__ float bf2f(unsigned short u) {
  union { unsigned u; float f; } v;
  v.u = ((unsigned)u) << 16;
  return v.f;
}
static __device__ __forceinline__ float fexp2(float x) {
  return __builtin_amdgcn_exp2f(x);
}
static __device__ __forceinline__ unsigned cvtpk_bf16(float a, float b) {
  unsigned r;
  asm("v_cvt_pk_bf16_f32 %0, %1, %2" : "=v"(r) : "v"(a), "v"(b));
  return r;
}

#define SC_LOG2 (0.35355339059327373f * 1.44269504088896f)

// ---------------------------------------------------------------------------
// 0) ALL weight conversions in one kernel: 9x 64x64 mats + W1 (64x256) + W2
// ---------------------------------------------------------------------------
__global__ __launch_bounds__(256) void k_wconv(
    const float* __restrict__ w0, const float* __restrict__ w1,
    const float* __restrict__ w2, const float* __restrict__ w3,
    const float* __restrict__ w4, const float* __restrict__ w5,
    const float* __restrict__ w6, const float* __restrict__ w7,
    const float* __restrict__ w8, const float* __restrict__ W1,
    const float* __restrict__ W2, unsigned short* __restrict__ WB,
    unsigned short* __restrict__ W1B, unsigned short* __restrict__ W2B) {
  int i = blockIdx.x * 256 + threadIdx.x;
  if (i < 36864) {
    const float* ws[9] = {w0, w1, w2, w3, w4, w5, w6, w7, w8};
    WB[i] = f2bf(ws[i >> 12][i & 4095]);
  } else if (i < 53248) {
    W1B[i - 36864] = f2bf(W1[i - 36864]);
  } else if (i < 69632) {
    W2B[i - 53248] = f2bf(W2[i - 53248]);
  }
}

// ---------------------------------------------------------------------------
// 1) fused accident-scale + graph linear, TRANSPOSED-PACKED output
// ---------------------------------------------------------------------------
__global__ __launch_bounds__(256) void k_lin64T(
    const float* __restrict__ x, const unsigned short* __restrict__ Wb,
    const float* __restrict__ bias, unsigned short* __restrict__ HP) {
  __shared__ unsigned short As[32][36];
  __shared__ unsigned short Bs[64][36];
  const int tid = threadIdx.x;
  const int r0 = blockIdx.x * 32;
  const int w = tid >> 6, l = tid & 63;
  const int rb = (w & 1) * 16, cb = (w >> 1) * 32;
  f32x4 acc0 = {0.f, 0.f, 0.f, 0.f}, acc1 = {0.f, 0.f, 0.f, 0.f};
  const int ar = tid >> 3, ak = (tid & 7) * 4;
  const int bc = tid & 63, bm0 = (tid >> 6) * 4;
  const int k4 = (l >> 4) * 4;
  const int arow = rb + (l & 15);
  const int bcol0 = cb + (l & 15);
  const float* xrow = x + (size_t)(r0 + ar) * 64;
  float sf = 1.0f + 0.3f * xrow[62] * __expf(-xrow[63] * (1.0f / 60.0f));
  for (int k0 = 0; k0 < 64; k0 += 32) {
    __syncthreads();
    float4 xv = *(const float4*)(xrow + k0 + ak);
    ushort4 xb;
    xb.x = f2bf(xv.x * sf); xb.y = f2bf(xv.y * sf);
    xb.z = f2bf(xv.z * sf); xb.w = f2bf(xv.w * sf);
    *(ushort4*)&As[ar][ak] = xb;
#pragma unroll
    for (int j = 0; j < 4; ++j) {
      int mp = bm0 + j;
      unsigned lo = Wb[(size_t)(k0 + 2 * mp) * 64 + bc];
      unsigned hi = Wb[(size_t)(k0 + 2 * mp + 1) * 64 + bc];
      *(unsigned*)&Bs[bc][2 * mp] = lo | (hi << 16);
    }
    __syncthreads();
    s16x4 alo = *(const s16x4*)&As[arow][k4];
    s16x4 ahi = *(const s16x4*)&As[arow][k4 + 16];
    s16x8 a = {alo.x, alo.y, alo.z, alo.w, ahi.x, ahi.y, ahi.z, ahi.w};
    s16x4 b0l = *(const s16x4*)&Bs[bcol0][k4];
    s16x4 b0h = *(const s16x4*)&Bs[bcol0][k4 + 16];
    s16x8 bf0 = {b0l.x, b0l.y, b0l.z, b0l.w, b0h.x, b0h.y, b0h.z, b0h.w};
    s16x4 b1l = *(const s16x4*)&Bs[bcol0 + 16][k4];
    s16x4 b1h = *(const s16x4*)&Bs[bcol0 + 16][k4 + 16];
    s16x8 bf1 = {b1l.x, b1l.y, b1l.z, b1l.w, b1h.x, b1h.y, b1h.z, b1h.w};
    acc0 = __builtin_amdgcn_mfma_f32_16x16x32_bf16(a, bf0, acc0, 0, 0, 0);
    acc1 = __builtin_amdgcn_mfma_f32_16x16x32_bf16(a, bf1, acc1, 0, 0, 0);
  }
  const int c0 = cb + (l & 15);
  float b0 = bias[c0], b1 = bias[c0 + 16];
#pragma unroll
  for (int r = 0; r < 4; ++r) {
    int row = r0 + rb + (l >> 4) * 4 + r;
    int bs = row / NN, m = row % NN;
    HP[((size_t)bs * 64 + c0) * NN + m] = f2bf(acc0[r] + b0);
    HP[((size_t)bs * 64 + c0 + 16) * NN + m] = f2bf(acc1[r] + b1);
  }
}

// ---------------------------------------------------------------------------
// 2) MFMA graph propagation + T14 async-stage split:
//    issue tile t+1's global loads BEFORE compute(t); LDS-write after barrier.
// ---------------------------------------------------------------------------
template <bool LAST>
__global__ __launch_bounds__(256) void k_prop_mfma(
    const float* __restrict__ adj,
    const unsigned short* __restrict__ HPin,
    const float* __restrict__ x,
    unsigned short* __restrict__ HPout,
    float* __restrict__ pout,
    unsigned short* __restrict__ pbout) {
  __shared__ unsigned short As[32][36];
  __shared__ unsigned short Bs[64][40];
  const int tid = threadIdx.x;
  const int bid = blockIdx.x;
  const int bs = bid / 25, mt = bid % 25;
  const int b = bs / NS;
  const int n0 = mt * 32;
  const float* abase = adj + (size_t)b * NN * NN + (size_t)n0 * NN;
  const unsigned short* hbase = HPin + (size_t)bs * 64 * NN;
  const int w = tid >> 6, l = tid & 63;
  const int rb = (w & 1) * 16;
  const int cb = (w >> 1) * 32;
  f32x4 acc0 = {0.f, 0.f, 0.f, 0.f}, acc1 = {0.f, 0.f, 0.f, 0.f};
  const int ar = tid >> 3, ak = (tid & 7) * 4;
  const int bc = tid & 63, bq = tid >> 6;
  const int k4 = (l >> 4) * 4;
  const int arow = rb + (l & 15);
  const int bcol0 = cb + (l & 15);
  // prologue: load tile 0 into regs
  float4 av = *(const float4*)(abase + (size_t)ar * NN + ak);
  s16x8 bv = *(const s16x8*)(hbase + (size_t)bc * NN + bq * 8);
  for (int m0 = 0; m0 < NN; m0 += 32) {
    __syncthreads();  // all reads of previous tile done
    {
      ushort4 ab;
      ab.x = f2bf(av.x); ab.y = f2bf(av.y);
      ab.z = f2bf(av.z); ab.w = f2bf(av.w);
      *(ushort4*)&As[ar][ak] = ab;
      *(s16x8*)&Bs[bc][bq * 8] = bv;
    }
    __syncthreads();  // staging visible
    // issue next tile's loads (latency hidden under compute below)
    if (m0 + 32 < NN) {
      av = *(const float4*)(abase + (size_t)ar * NN + m0 + 32 + ak);
      bv = *(const s16x8*)(hbase + (size_t)bc * NN + m0 + 32 + bq * 8);
    }
    s16x4 alo = *(const s16x4*)&As[arow][k4];
    s16x4 ahi = *(const s16x4*)&As[arow][k4 + 16];
    s16x8 a = {alo.x, alo.y, alo.z, alo.w, ahi.x, ahi.y, ahi.z, ahi.w};
    s16x4 b0l = *(const s16x4*)&Bs[bcol0][k4];
    s16x4 b0h = *(const s16x4*)&Bs[bcol0][k4 + 16];
    s16x8 bf0 = {b0l.x, b0l.y, b0l.z, b0l.w, b0h.x, b0h.y, b0h.z, b0h.w};
    s16x4 b1l = *(const s16x4*)&Bs[bcol0 + 16][k4];
    s16x4 b1h = *(const s16x4*)&Bs[bcol0 + 16][k4 + 16];
    s16x8 bf1 = {b1l.x, b1l.y, b1l.z, b1l.w, b1h.x, b1h.y, b1h.z, b1h.w};
    acc0 = __builtin_amdgcn_mfma_f32_16x16x32_bf16(a, bf0, acc0, 0, 0, 0);
    acc1 = __builtin_amdgcn_mfma_f32_16x16x32_bf16(a, bf1, acc1, 0, 0, 0);
  }
  const int c0 = cb + (l & 15);
  if (LAST) {
#pragma unroll
    for (int r = 0; r < 4; ++r) {
      int n = n0 + rb + (l >> 4) * 4 + r;
      float v0 = fmaxf(acc0[r], 0.f);
      float v1 = fmaxf(acc1[r], 0.f);
      size_t i0 = ((size_t)bs * NN + n) * 64 + c0;
      size_t i1 = i0 + 16;
      float p0 = v0 + x[i0], p1 = v1 + x[i1];
      pout[i0] = p0;
      pout[i1] = p1;
      pbout[i0] = f2bf(p0);
      pbout[i1] = f2bf(p1);
    }
  } else {
    int nb = n0 + rb + (l >> 4) * 4;
    s16x4 o0, o1;
#pragma unroll
    for (int r = 0; r < 4; ++r) {
      o0[r] = (short)f2bf(fmaxf(acc0[r], 0.f));
      o1[r] = (short)f2bf(fmaxf(acc1[r], 0.f));
    }
    *(s16x4*)&HPout[((size_t)bs * 64 + c0) * NN + nb] = o0;
    *(s16x4*)&HPout[((size_t)bs * 64 + c0 + 16) * NN + nb] = o1;
  }
}

// ---------------------------------------------------------------------------
// 3) MFMA fused QKV (bf16 out); Q scaled by qscale
// ---------------------------------------------------------------------------
__global__ __launch_bounds__(256) void k_qkv_mfma(
    const unsigned short* __restrict__ Xb,
    const unsigned short* __restrict__ Wq,
    const unsigned short* __restrict__ Wk,
    const unsigned short* __restrict__ Wv,
    const float* __restrict__ bq, const float* __restrict__ bk,
    const float* __restrict__ bv, float qscale,
    unsigned short* __restrict__ Qo, unsigned short* __restrict__ Ko,
    unsigned short* __restrict__ Vo) {
  __shared__ unsigned short As[32][36];
  __shared__ unsigned short Bs[3][64][36];
  const int tid = threadIdx.x;
  const int r0 = blockIdx.x * 32;
  const int w = tid >> 6, l = tid & 63;
  const int rb = (w & 1) * 16;
  const int cb = (w >> 1) * 32;
  f32x4 acc[3][2];
#pragma unroll
  for (int i = 0; i < 3; ++i)
#pragma unroll
    for (int j = 0; j < 2; ++j) acc[i][j] = (f32x4){0.f, 0.f, 0.f, 0.f};
  const unsigned short* Wm[3] = {Wq, Wk, Wv};
  const int ar = tid >> 3, ak = (tid & 7) * 4;
  const int bc = tid & 63, bm0 = (tid >> 6) * 4;
  const int k4 = (l >> 4) * 4;
  const int arow = rb + (l & 15);
  const int bcol0 = cb + (l & 15);
  for (int k0 = 0; k0 < 64; k0 += 32) {
    __syncthreads();
    *(s16x4*)&As[ar][ak] =
        *(const s16x4*)(Xb + (size_t)(r0 + ar) * 64 + k0 + ak);
#pragma unroll
    for (int wm = 0; wm < 3; ++wm) {
#pragma unroll
      for (int j = 0; j < 4; ++j) {
        int mp = bm0 + j;
        unsigned lo = Wm[wm][(size_t)(k0 + 2 * mp) * 64 + bc];
        unsigned hi = Wm[wm][(size_t)(k0 + 2 * mp + 1) * 64 + bc];
        *(unsigned*)&Bs[wm][bc][2 * mp] = lo | (hi << 16);
      }
    }
    __syncthreads();
    s16x4 alo = *(const s16x4*)&As[arow][k4];
    s16x4 ahi = *(const s16x4*)&As[arow][k4 + 16];
    s16x8 a = {alo.x, alo.y, alo.z, alo.w, ahi.x, ahi.y, ahi.z, ahi.w};
#pragma unroll
    for (int wm = 0; wm < 3; ++wm) {
      s16x4 b0l = *(const s16x4*)&Bs[wm][bcol0][k4];
      s16x4 b0h = *(const s16x4*)&Bs[wm][bcol0][k4 + 16];
      s16x8 bf0 = {b0l.x, b0l.y, b0l.z, b0l.w, b0h.x, b0h.y, b0h.z, b0h.w};
      s16x4 b1l = *(const s16x4*)&Bs[wm][bcol0 + 16][k4];
      s16x4 b1h = *(const s16x4*)&Bs[wm][bcol0 + 16][k4 + 16];
      s16x8 bf1 = {b1l.x, b1l.y, b1l.z, b1l.w, b1h.x, b1h.y, b1h.z, b1h.w};
      acc[wm][0] = __builtin_amdgcn_mfma_f32_16x16x32_bf16(a, bf0, acc[wm][0], 0, 0, 0);
      acc[wm][1] = __builtin_amdgcn_mfma_f32_16x16x32_bf16(a, bf1, acc[wm][1], 0, 0, 0);
    }
  }
  const float* bm[3] = {bq, bk, bv};
  unsigned short* Om[3] = {Qo, Ko, Vo};
  const int c0 = cb + (l & 15);
#pragma unroll
  for (int wm = 0; wm < 3; ++wm) {
    float b0 = bm[wm][c0], b1 = bm[wm][c0 + 16];
    float sc = (wm == 0) ? qscale : 1.0f;
#pragma unroll
    for (int r = 0; r < 4; ++r) {
      int row = r0 + rb + (l >> 4) * 4 + r;
      Om[wm][(size_t)row * 64 + c0] = f2bf((acc[wm][0][r] + b0) * sc);
      Om[wm][(size_t)row * 64 + c0 + 16] = f2bf((acc[wm][1][r] + b1) * sc);
    }
  }
}

// ---------------------------------------------------------------------------
// 4) spatial attention v5: fixed-max flash + unroll-5 tile pipeline.
// ---------------------------------------------------------------------------
__global__ __launch_bounds__(256) void k_sattn5(
    const unsigned short* __restrict__ Qb,
    const unsigned short* __restrict__ Kb,
    const unsigned short* __restrict__ Vb,
    unsigned short* __restrict__ OB) {
  __shared__ unsigned short Ks[800][8];
  __shared__ unsigned short Vt[25 * 256 + 256];  // pad for masked OOB reads
  const int bs = blockIdx.x, h = blockIdx.y;
  const int tid = threadIdx.x;
  const size_t base = (size_t)bs * NN * 64 + h * DH;
  for (int r = tid; r < NN; r += 256)
    *(s16x8*)&Ks[r][0] = *(const s16x8*)(Kb + base + (size_t)r * 64);
  if (tid < 200) {
    int t = tid >> 3, c = tid & 7;
    int r = t * 32 + c * 4;
    s16x8 v0 = *(const s16x8*)(Vb + base + (size_t)r * 64);
    s16x8 v1 = *(const s16x8*)(Vb + base + (size_t)(r + 1) * 64);
    s16x8 v2 = *(const s16x8*)(Vb + base + (size_t)(r + 2) * 64);
    s16x8 v3 = *(const s16x8*)(Vb + base + (size_t)(r + 3) * 64);
#pragma unroll
    for (int d = 0; d < 8; ++d) {
      unsigned lo = (unsigned short)v0[d] | ((unsigned)(unsigned short)v1[d] << 16);
      unsigned hi = (unsigned short)v2[d] | ((unsigned)(unsigned short)v3[d] << 16);
      unsigned* dst = (unsigned*)&Vt[t * 256 + d * 32 + ((c ^ d) & 7) * 4];
      dst[0] = lo;
      dst[1] = hi;
    }
  }
  __syncthreads();
  const int w = tid >> 6, l = tid & 63;
  const int q0 = blockIdx.z * 128 + w * 32;
  if (q0 >= NN) return;
  const int r15 = l & 15, g = l >> 4;
  const int dd = r15;
  const int off1 = dd * 32 + ((g ^ dd) & 7) * 4;
  const int off2 = dd * 32 + (((4 + g) ^ dd) & 7) * 4;
  s16x4 qvA = *(const s16x4*)(Qb + base + (size_t)(q0 + r15) * 64 + (g & 1) * 4);
  s16x4 qvB = *(const s16x4*)(Qb + base + (size_t)(q0 + 16 + r15) * 64 + (g & 1) * 4);
  s16x8 qfA = {0, 0, 0, 0, 0, 0, 0, 0};
  s16x8 qfB = {0, 0, 0, 0, 0, 0, 0, 0};
  if (g < 2) {
    qfA[0] = qvA.x; qfA[1] = qvA.y; qfA[2] = qvA.z; qfA[3] = qvA.w;
    qfB[0] = qvB.x; qfB[1] = qvB.y; qfB[2] = qvB.z; qfB[3] = qvB.w;
  }
  const short one_bf = (short)0x3F80;
  f32x4 accA = {0.f, 0.f, 0.f, 0.f}, accB = {0.f, 0.f, 0.f, 0.f};
  const f32x4 zero4 = {0.f, 0.f, 0.f, 0.f};
#pragma unroll 5
  for (int t = 0; t < 25; ++t) {
    s16x4 ka = *(const s16x4*)&Ks[t * 32 + r15][(g & 1) * 4];
    s16x4 kb = *(const s16x4*)&Ks[t * 32 + 16 + r15][(g & 1) * 4];
    s16x8 kfa = {0, 0, 0, 0, 0, 0, 0, 0};
    s16x8 kfb = {0, 0, 0, 0, 0, 0, 0, 0};
    if (g < 2) {
      kfa[0] = ka.x; kfa[1] = ka.y; kfa[2] = ka.z; kfa[3] = ka.w;
      kfb[0] = kb.x; kfb[1] = kb.y; kfb[2] = kb.z; kfb[3] = kb.w;
    }
    s16x4 va = *(const s16x4*)&Vt[t * 256 + off1];
    s16x4 vb = *(const s16x4*)&Vt[t * 256 + off2];
    s16x8 vf;
    if (dd < 8) {
      vf = (s16x8){va.x, va.y, va.z, va.w, vb.x, vb.y, vb.z, vb.w};
    } else if (dd == 8) {
      vf = (s16x8){one_bf, one_bf, one_bf, one_bf, one_bf, one_bf, one_bf, one_bf};
    } else {
      vf = (s16x8){0, 0, 0, 0, 0, 0, 0, 0};
    }
    f32x4 sA1 = __builtin_amdgcn_mfma_f32_16x16x32_bf16(kfa, qfA, zero4, 0, 0, 0);
    f32x4 sA2 = __builtin_amdgcn_mfma_f32_16x16x32_bf16(kfb, qfA, zero4, 0, 0, 0);
    f32x4 sB1 = __builtin_amdgcn_mfma_f32_16x16x32_bf16(kfa, qfB, zero4, 0, 0, 0);
    f32x4 sB2 = __builtin_amdgcn_mfma_f32_16x16x32_bf16(kfb, qfB, zero4, 0, 0, 0);
    float pA[8], pB[8];
#pragma unroll
    for (int r = 0; r < 4; ++r) {
      pA[r] = fexp2(sA1[r]);
      pA[4 + r] = fexp2(sA2[r]);
      pB[r] = fexp2(sB1[r]);
      pB[4 + r] = fexp2(sB2[r]);
    }
    union { unsigned u[4]; s16x8 v; } puA, puB;
    puA.u[0] = cvtpk_bf16(pA[0], pA[1]);
    puA.u[1] = cvtpk_bf16(pA[2], pA[3]);
    puA.u[2] = cvtpk_bf16(pA[4], pA[5]);
    puA.u[3] = cvtpk_bf16(pA[6], pA[7]);
    puB.u[0] = cvtpk_bf16(pB[0], pB[1]);
    puB.u[1] = cvtpk_bf16(pB[2], pB[3]);
    puB.u[2] = cvtpk_bf16(pB[4], pB[5]);
    puB.u[3] = cvtpk_bf16(pB[6], pB[7]);
    accA = __builtin_amdgcn_mfma_f32_16x16x32_bf16(vf, puA.v, accA, 0, 0, 0);
    accB = __builtin_amdgcn_mfma_f32_16x16x32_bf16(vf, puB.v, accB, 0, 0, 0);
  }
  float lsA = __shfl(accA[0], 32 + r15, 64);
  float lsB = __shfl(accB[0], 32 + r15, 64);
  float invA = 1.f / lsA;
  float invB = 1.f / lsB;
  if (g < 2) {
#pragma unroll
    for (int r = 0; r < 4; ++r) {
      int d = g * 4 + r;
      OB[base + (size_t)(q0 + r15) * 64 + d] = f2bf(accA[r] * invA);
      OB[base + (size_t)(q0 + 16 + r15) * 64 + d] = f2bf(accB[r] * invB);
    }
  }
}

// ---------------------------------------------------------------------------
// 5) MFMA proj + residual + LN (K=64).
//    LN2=false: bfout = bf16 copy of LN output.
//    LN2=true:  bfout = bf16( LN(LN_output; g2, be2) )  (fused second LN)
// ---------------------------------------------------------------------------
template <bool LN2>
__global__ __launch_bounds__(256) void k_projln_mfma(
    const unsigned short* __restrict__ Xb,
    const unsigned short* __restrict__ Wb,
    const float* __restrict__ bias, const float* __restrict__ res,
    const float* __restrict__ g, const float* __restrict__ be,
    const float* __restrict__ g2, const float* __restrict__ be2,
    float* __restrict__ out, unsigned short* __restrict__ bfout) {
  __shared__ unsigned short As[32][36];
  __shared__ unsigned short Bs[64][36];
  __shared__ float CT[32][68];
  const int tid = threadIdx.x;
  const int r0 = blockIdx.x * 32;
  const int w = tid >> 6, l = tid & 63;
  const int rb = (w & 1) * 16, cb = (w >> 1) * 32;
  f32x4 acc0 = {0.f, 0.f, 0.f, 0.f}, acc1 = {0.f, 0.f, 0.f, 0.f};
  const int ar = tid >> 3, ak = (tid & 7) * 4;
  const int bc = tid & 63, bm0 = (tid >> 6) * 4;
  const int k4 = (l >> 4) * 4;
  const int arow = rb + (l & 15);
  const int bcol0 = cb + (l & 15);
  for (int k0 = 0; k0 < 64; k0 += 32) {
    __syncthreads();
    *(s16x4*)&As[ar][ak] = *(const s16x4*)(Xb + (size_t)(r0 + ar) * 64 + k0 + ak);
#pragma unroll
    for (int j = 0; j < 4; ++j) {
      int mp = bm0 + j;
      unsigned lo = Wb[(size_t)(k0 + 2 * mp) * 64 + bc];
      unsigned hi = Wb[(size_t)(k0 + 2 * mp + 1) * 64 + bc];
      *(unsigned*)&Bs[bc][2 * mp] = lo | (hi << 16);
    }
    __syncthreads();
    s16x4 alo = *(const s16x4*)&As[arow][k4];
    s16x4 ahi = *(const s16x4*)&As[arow][k4 + 16];
    s16x8 a = {alo.x, alo.y, alo.z, alo.w, ahi.x, ahi.y, ahi.z, ahi.w};
    s16x4 b0l = *(const s16x4*)&Bs[bcol0][k4];
    s16x4 b0h = *(const s16x4*)&Bs[bcol0][k4 + 16];
    s16x8 bf0 = {b0l.x, b0l.y, b0l.z, b0l.w, b0h.x, b0h.y, b0h.z, b0h.w};
    s16x4 b1l = *(const s16x4*)&Bs[bcol0 + 16][k4];
    s16x4 b1h = *(const s16x4*)&Bs[bcol0 + 16][k4 + 16];
    s16x8 bf1 = {b1l.x, b1l.y, b1l.z, b1l.w, b1h.x, b1h.y, b1h.z, b1h.w};
    acc0 = __builtin_amdgcn_mfma_f32_16x16x32_bf16(a, bf0, acc0, 0, 0, 0);
    acc1 = __builtin_amdgcn_mfma_f32_16x16x32_bf16(a, bf1, acc1, 0, 0, 0);
  }
  const int c0 = cb + (l & 15);
#pragma unroll
  for (int r = 0; r < 4; ++r) {
    int row = rb + (l >> 4) * 4 + r;
    size_t gi = (size_t)(r0 + row) * 64;
    CT[row][c0] = acc0[r] + bias[c0] + res[gi + c0];
    CT[row][c0 + 16] = acc1[r] + bias[c0 + 16] + res[gi + c0 + 16];
  }
  __syncthreads();
  const int row = tid >> 3, sub = tid & 7;
  float v[8];
#pragma unroll
  for (int i = 0; i < 8; ++i) v[i] = CT[row][sub * 8 + i];
  float s = 0.f;
#pragma unroll
  for (int i = 0; i < 8; ++i) s += v[i];
#pragma unroll
  for (int off = 1; off < 8; off <<= 1) s += __shfl_xor(s, off, 64);
  float mean = s * (1.f / 64.f);
  float q = 0.f;
#pragma unroll
  for (int i = 0; i < 8; ++i) {
    float ddd = v[i] - mean;
    q += ddd * ddd;
  }
#pragma unroll
  for (int off = 1; off < 8; off <<= 1) q += __shfl_xor(q, off, 64);
  float rstd = rsqrtf(q * (1.f / 64.f) + 1e-5f);
  float r4[8];
#pragma unroll
  for (int i = 0; i < 8; ++i)
    r4[i] = (v[i] - mean) * rstd * g[sub * 8 + i] + be[sub * 8 + i];
  float* op = out + (size_t)(r0 + row) * 64 + sub * 8;
  *(float4*)op = (float4){r4[0], r4[1], r4[2], r4[3]};
  *(float4*)(op + 4) = (float4){r4[4], r4[5], r4[6], r4[7]};
  unsigned short* bp = bfout + (size_t)(r0 + row) * 64 + sub * 8;
  if (!LN2) {
#pragma unroll
    for (int i = 0; i < 8; ++i) bp[i] = f2bf(r4[i]);
  } else {
    float s2 = 0.f;
#pragma unroll
    for (int i = 0; i < 8; ++i) s2 += r4[i];
#pragma unroll
    for (int off = 1; off < 8; off <<= 1) s2 += __shfl_xor(s2, off, 64);
    float mean2 = s2 * (1.f / 64.f);
    float q2 = 0.f;
#pragma unroll
    for (int i = 0; i < 8; ++i) {
      float d2 = r4[i] - mean2;
      q2 += d2 * d2;
    }
#pragma unroll
    for (int off = 1; off < 8; off <<= 1) q2 += __shfl_xor(q2, off, 64);
    float rstd2 = rsqrtf(q2 * (1.f / 64.f) + 1e-5f);
#pragma unroll
    for (int i = 0; i < 8; ++i)
      bp[i] = f2bf((r4[i] - mean2) * rstd2 * g2[sub * 8 + i] + be2[sub * 8 + i]);
  }
}

// ---------------------------------------------------------------------------
// 6) temporal attention: one block per (b,n), L = 12; bf16 in/out
// ---------------------------------------------------------------------------
__global__ __launch_bounds__(256) void k_tattn(
    const unsigned short* __restrict__ Q, const unsigned short* __restrict__ K,
    const unsigned short* __restrict__ V, unsigned short* __restrict__ O) {
  int b = blockIdx.x / NN, n = blockIdx.x % NN;
  __shared__ float Qs[12][64], Ks[12][64], Vs[12][64];
  int tid = threadIdx.x;
  for (int i = tid; i < 12 * 64; i += 256) {
    int s = i >> 6, c = i & 63;
    size_t idx = (((size_t)b * NS + s) * NN + n) * 64 + c;
    Qs[s][c] = bf2f(Q[idx]);
    Ks[s][c] = bf2f(K[idx]);
    Vs[s][c] = bf2f(V[idx]);
  }
  __syncthreads();
  for (int wi = tid; wi < 12 * 64; wi += 256) {
    int l = wi >> 6, c = wi & 63;
    int h8 = c & 56;
    float sc[12];
    float mx = -1e30f;
#pragma unroll
    for (int m = 0; m < 12; ++m) {
      float s = 0.f;
#pragma unroll
      for (int d = 0; d < 8; ++d) s += Qs[l][h8 + d] * Ks[m][h8 + d];
      s *= 0.35355339059327373f;
      sc[m] = s;
      mx = fmaxf(mx, s);
    }
    float sum = 0.f;
#pragma unroll
    for (int m = 0; m < 12; ++m) {
      sc[m] = __expf(sc[m] - mx);
      sum += sc[m];
    }
    float inv = 1.f / sum;
    float o = 0.f;
#pragma unroll
    for (int m = 0; m < 12; ++m) o += sc[m] * Vs[m][c];
    size_t idx = (((size_t)b * NS + l) * NN + n) * 64 + c;
    O[idx] = f2bf(o * inv);
  }
}

// ---------------------------------------------------------------------------
// 7) Fused FFN: out = LN( relu(Xb@W1+b1)@W2 + b2 + res ; g, be )
// ---------------------------------------------------------------------------
__global__ __launch_bounds__(256) void k_ffn_fused(
    const unsigned short* __restrict__ Xb,   // [NR][64] bf16 (LN1 output)
    const unsigned short* __restrict__ W1b,  // [64][256] bf16
    const float* __restrict__ b1,
    const unsigned short* __restrict__ W2b,  // [256][64] bf16
    const float* __restrict__ b2,
    const float* __restrict__ res,           // [NR][64] f32 (attn_out)
    const float* __restrict__ g, const float* __restrict__ be,
    float* __restrict__ out) {
  __shared__ unsigned short As[32][68];
  __shared__ unsigned short Bs[64][66];
  __shared__ unsigned short Hs[32][264];
  __shared__ float CT[32][68];
  const int tid = threadIdx.x;
  const int r0 = blockIdx.x * 32;
  const int w = tid >> 6, l = tid & 63;
  const int rb = (w & 1) * 16, cb = (w >> 1) * 32;
  const int r15 = l & 15;
  const int k4 = (l >> 4) * 4;
  const int arow = rb + r15;
  const int bcol0 = cb + r15;
  {
    int ar = tid >> 3, ak8 = (tid & 7) * 8;
    *(s16x8*)&As[ar][ak8] = *(const s16x8*)(Xb + (size_t)(r0 + ar) * 64 + ak8);
  }
  const int sbc = tid & 63;
  for (int c = 0; c < 4; ++c) {
    __syncthreads();
    {
      const int smp0 = (tid >> 6) * 8;
      int gcol = c * 64 + sbc;
#pragma unroll
      for (int j = 0; j < 8; ++j) {
        int mp = smp0 + j;
        unsigned lo = W1b[(size_t)(2 * mp) * 256 + gcol];
        unsigned hi = W1b[(size_t)(2 * mp + 1) * 256 + gcol];
        *(unsigned*)&Bs[sbc][2 * mp] = lo | (hi << 16);
      }
    }
    __syncthreads();
    f32x4 acc0 = {0.f, 0.f, 0.f, 0.f}, acc1 = {0.f, 0.f, 0.f, 0.f};
#pragma unroll
    for (int k0 = 0; k0 < 64; k0 += 32) {
      s16x4 alo = *(const s16x4*)&As[arow][k0 + k4];
      s16x4 ahi = *(const s16x4*)&As[arow][k0 + k4 + 16];
      s16x8 a = {alo.x, alo.y, alo.z, alo.w, ahi.x, ahi.y, ahi.z, ahi.w};
      s16x4 b0l = *(const s16x4*)&Bs[bcol0][k0 + k4];
      s16x4 b0h = *(const s16x4*)&Bs[bcol0][k0 + k4 + 16];
      s16x8 bf0 = {b0l.x, b0l.y, b0l.z, b0l.w, b0h.x, b0h.y, b0h.z, b0h.w};
      s16x4 b1l = *(const s16x4*)&Bs[bcol0 + 16][k0 + k4];
      s16x4 b1h = *(const s16x4*)&Bs[bcol0 + 16][k0 + k4 + 16];
      s16x8 bf1 = {b1l.x, b1l.y, b1l.z, b1l.w, b1h.x, b1h.y, b1h.z, b1h.w};
      acc0 = __builtin_amdgcn_mfma_f32_16x16x32_bf16(a, bf0, acc0, 0, 0, 0);
      acc1 = __builtin_amdgcn_mfma_f32_16x16x32_bf16(a, bf1, acc1, 0, 0, 0);
    }
    int c0 = cb + r15;
    float bb0 = b1[c * 64 + c0], bb1v = b1[c * 64 + c0 + 16];
#pragma unroll
    for (int r = 0; r < 4; ++r) {
      int row = rb + (l >> 4) * 4 + r;
      Hs[row][c * 64 + c0] = f2bf(fmaxf(acc0[r] + bb0, 0.f));
      Hs[row][c * 64 + c0 + 16] = f2bf(fmaxf(acc1[r] + bb1v, 0.f));
    }
  }
  f32x4 acc0 = {0.f, 0.f, 0.f, 0.f}, acc1 = {0.f, 0.f, 0.f, 0.f};
  const int smp4 = (tid >> 6) * 4;
  for (int k0 = 0; k0 < 256; k0 += 32) {
    __syncthreads();
#pragma unroll
    for (int j = 0; j < 4; ++j) {
      int mp = smp4 + j;
      unsigned lo = W2b[(size_t)(k0 + 2 * mp) * 64 + sbc];
      unsigned hi = W2b[(size_t)(k0 + 2 * mp + 1) * 64 + sbc];
      *(unsigned*)&Bs[sbc][2 * mp] = lo | (hi << 16);
    }
    __syncthreads();
    s16x4 alo = *(const s16x4*)&Hs[arow][k0 + k4];
    s16x4 ahi = *(const s16x4*)&Hs[arow][k0 + k4 + 16];
    s16x8 a = {alo.x, alo.y, alo.z, alo.w, ahi.x, ahi.y, ahi.z, ahi.w};
    s16x4 b0l = *(const s16x4*)&Bs[bcol0][k4];
    s16x4 b0h = *(const s16x4*)&Bs[bcol0][k4 + 16];
    s16x8 bf0 = {b0l.x, b0l.y, b0l.z, b0l.w, b0h.x, b0h.y, b0h.z, b0h.w};
    s16x4 b1l = *(const s16x4*)&Bs[bcol0 + 16][k4];
    s16x4 b1h = *(const s16x4*)&Bs[bcol0 + 16][k4 + 16];
    s16x8 bf1 = {b1l.x, b1l.y, b1l.z, b1l.w, b1h.x, b1h.y, b1h.z, b1h.w};
    acc0 = __builtin_amdgcn_mfma_f32_16x16x32_bf16(a, bf0, acc0, 0, 0, 0);
    acc1 = __builtin_amdgcn_mfma_f32_16x16x32_bf16(a, bf1, acc1, 0, 0, 0);
  }
  const int c0 = cb + r15;
#pragma unroll
  for (int r = 0; r < 4; ++r) {
    int row = rb + (l >> 4) * 4 + r;
    size_t gi = (size_t)(r0 + row) * 64;
    CT[row][c0] = acc0[r] + b2[c0] + res[gi + c0];
    CT[row][c0 + 16] = acc1[r] + b2[c0 + 16] + res[gi + c0 + 16];
  }
  __syncthreads();
  const int row = tid >> 3, sub = tid & 7;
  float v[8];
#pragma unroll
  for (int i = 0; i < 8; ++i) v[i] = CT[row][sub * 8 + i];
  float s = 0.f;
#pragma unroll
  for (int i = 0; i < 8; ++i) s += v[i];
#pragma unroll
  for (int off = 1; off < 8; off <<= 1) s += __shfl_xor(s, off, 64);
  float mean = s * (1.f / 64.f);
  float q = 0.f;
#pragma unroll
  for (int i = 0; i < 8; ++i) {
    float d = v[i] - mean;
    q += d * d;
  }
#pragma unroll
  for (int off = 1; off < 8; off <<= 1) q += __shfl_xor(q, off, 64);
  float rstd = rsqrtf(q * (1.f / 64.f) + 1e-5f);
  float r4[8];
#pragma unroll
  for (int i = 0; i < 8; ++i)
    r4[i] = (v[i] - mean) * rstd * g[sub * 8 + i] + be[sub * 8 + i];
  float* op = out + (size_t)(r0 + row) * 64 + sub * 8;
  *(float4*)op = (float4){r4[0], r4[1], r4[2], r4[3]};
  *(float4*)(op + 4) = (float4){r4[4], r4[5], r4[6], r4[7]};
}

// ---------------------------------------------------------------------------
extern "C" void kernel_launch(void* const* d_in, const int* in_sizes, int n_in,
                              void* d_out, int out_size, void* d_ws,
                              size_t ws_size, hipStream_t stream) {
  const float* x = (const float*)d_in[0];
  const float* adj = (const float*)d_in[1];
  const float* W_gp = (const float*)d_in[2];
  const float* b_gp = (const float*)d_in[3];
  const float* Wq_s = (const float*)d_in[4];
  const float* Wk_s = (const float*)d_in[5];
  const float* Wv_s = (const float*)d_in[6];
  const float* Wo_s = (const float*)d_in[7];
  const float* bq_s = (const float*)d_in[8];
  const float* bk_s = (const float*)d_in[9];
  const float* bv_s = (const float*)d_in[10];
  const float* bo_s = (const float*)d_in[11];
  const float* g_s = (const float*)d_in[12];
  const float* be_s = (const float*)d_in[13];
  const float* Wq_t = (const float*)d_in[14];
  const float* Wk_t = (const float*)d_in[15];
  const float* Wv_t = (const float*)d_in[16];
  const float* Wo_t = (const float*)d_in[17];
  const float* bq_t = (const float*)d_in[18];
  const float* bk_t = (const float*)d_in[19];
  const float* bv_t = (const float*)d_in[20];
  const float* bo_t = (const float*)d_in[21];
  const float* g_t = (const float*)d_in[22];
  const float* be_t = (const float*)d_in[23];
  const float* W1 = (const float*)d_in[24];
  const float* b1 = (const float*)d_in[25];
  const float* W2 = (const float*)d_in[26];
  const float* b2 = (const float*)d_in[27];
  const float* g1 = (const float*)d_in[28];
  const float* be1 = (const float*)d_in[29];
  const float* g2 = (const float*)d_in[30];
  const float* be2 = (const float*)d_in[31];
  float* out = (float*)d_out;

  float* ws = (float*)d_ws;
  const size_t U = (size_t)NR * 64;  // 1,228,800 floats
  float* A = ws + 0 * U;
  float* Bb = ws + 1 * U;
  float* C = ws + 2 * U;
  float* D = ws + 3 * U;
  float* P = ws + 4 * U;
  // bf16 overlays
  unsigned short* QB = (unsigned short*)A;    // spatial Q
  unsigned short* KB = (unsigned short*)Bb;   // spatial K
  unsigned short* VB = (unsigned short*)C;    // spatial V
  unsigned short* OBuf = (unsigned short*)D;  // sattn out
  unsigned short* Q2 = (unsigned short*)C;    // temporal Q (spatial done)
  unsigned short* K2 = (unsigned short*)D;
  unsigned short* V2 = (unsigned short*)(ws + 5 * U + U);  // after PB region
  unsigned short* PB = (unsigned short*)(ws + 5 * U);
  unsigned short* LNB = (unsigned short*)(ws + 7 * U);  // also TB
  unsigned short* TB = LNB;
  unsigned short* W1B = (unsigned short*)(ws + 7 * U + U / 2);
  unsigned short* W2B = W1B + 16384;
  unsigned short* HP0 = (unsigned short*)(ws + 9 * U);
  unsigned short* HP1 = (unsigned short*)(ws + 9 * U + U / 2);
  unsigned short* WB = (unsigned short*)(ws + 10 * U + 650240);  // 9*4096 sh

  dim3 blk(256);
  // 0) all weight conversions (one launch)
  k_wconv<<<272, blk, 0, stream>>>(Wq_s, Wk_s, Wv_s, Wq_t, Wk_t, Wv_t, W_gp,
                                   Wo_s, Wo_t, W1, W2, WB, W1B, W2B);
  // 1) fused accident-scale + graph linear -> HP0 (transposed-packed bf16)
  k_lin64T<<<NR / 32, blk, 0, stream>>>(x, WB + 6 * 4096, b_gp, HP0);
  // 2) 3 MFMA propagation steps (async-stage split)
  k_prop_mfma<false><<<NBS * 25, blk, 0, stream>>>(adj, HP0, x, HP1, P, PB);
  k_prop_mfma<false><<<NBS * 25, blk, 0, stream>>>(adj, HP1, x, HP0, P, PB);
  k_prop_mfma<true><<<NBS * 25, blk, 0, stream>>>(adj, HP0, x, HP1, P, PB);
  // 3) spatial: QKV (Q pre-scaled) -> sattn5 -> proj+LN -> A (f32) + PB
  k_qkv_mfma<<<NR / 32, blk, 0, stream>>>(PB, WB, WB + 4096, WB + 8192, bq_s,
                                          bk_s, bv_s, SC_LOG2, QB, KB, VB);
  k_sattn5<<<dim3(NBS, HEADS, 7), blk, 0, stream>>>(QB, KB, VB, OBuf);
  k_projln_mfma<false><<<NR / 32, blk, 0, stream>>>(
      OBuf, WB + 7 * 4096, bo_s, P, g_s, be_s, nullptr, nullptr, A, PB);
  // 4) temporal: QKV -> tattn -> proj+LN_t (+fused LN1) -> Bb (f32) + LNB
  k_qkv_mfma<<<NR / 32, blk, 0, stream>>>(PB, WB + 12288, WB + 16384,
                                          WB + 20480, bq_t, bk_t, bv_t, 1.0f,
                                          Q2, K2, V2);
  k_tattn<<<NB * NN, blk, 0, stream>>>(Q2, K2, V2, TB);
  k_projln_mfma<true><<<NR / 32, blk, 0, stream>>>(
      TB, WB + 8 * 4096, bo_t, A, g_t, be_t, g1, be1, Bb, LNB);
  // 5) fused FFN (ffn1 + ffn2 + residual + final LN) -> out
  k_ffn_fused<<<NR / 32, blk, 0, stream>>>(LNB, W1B, b1, W2B, b2, Bb, g2, be2,
                                           out);
}

// Round 11
// 136.739 us; speedup vs baseline: 1.1574x; 1.1022x over previous
//
#include <hip/hip_runtime.h>
#include <hip/hip_bf16.h>

#define NB 2
#define NS 12
#define NN 800
#define HEADS 8
#define DH 8
#define NBS (NB*NS)        // 24
#define NR (NB*NS*NN)      // 19200 rows

typedef __attribute__((ext_vector_type(4))) float f32x4;
typedef __attribute__((ext_vector_type(4))) short s16x4;
typedef __attribute__((ext_vector_type(8))) short s16x8;

static __device__ __forceinline__ unsigned short f2bf(float f) {
  union { float f; unsigned u; } v; v.f = f;
  unsigned r = (v.u + 0x7FFFu + ((v.u >> 16) & 1u)) >> 16;
  return (unsigned short)r;
}
static __device__ __forceinline__ float bf2f(unsigned short u) {
  union { unsigned u; float f; } v;
  v.u = ((unsigned)u) << 16;
  return v.f;
}
static __device__ __forceinline__ float fexp2(float x) {
  return __builtin_amdgcn_exp2f(x);
}
static __device__ __forceinline__ unsigned cvtpk_bf16(float a, float b) {
  unsigned r;
  asm("v_cvt_pk_bf16_f32 %0, %1, %2" : "=v"(r) : "v"(a), "v"(b));
  return r;
}

#define SC_LOG2 (0.35355339059327373f * 1.44269504088896f)

// ---------------------------------------------------------------------------
// 0) ALL weight conversions in one kernel
// ---------------------------------------------------------------------------
__global__ __launch_bounds__(256) void k_wconv(
    const float* __restrict__ w0, const float* __restrict__ w1,
    const float* __restrict__ w2, const float* __restrict__ w3,
    const float* __restrict__ w4, const float* __restrict__ w5,
    const float* __restrict__ w6, const float* __restrict__ w7,
    const float* __restrict__ w8, const float* __restrict__ W1,
    const float* __restrict__ W2, unsigned short* __restrict__ WB,
    unsigned short* __restrict__ W1B, unsigned short* __restrict__ W2B) {
  int i = blockIdx.x * 256 + threadIdx.x;
  if (i < 36864) {
    const float* ws[9] = {w0, w1, w2, w3, w4, w5, w6, w7, w8};
    WB[i] = f2bf(ws[i >> 12][i & 4095]);
  } else if (i < 53248) {
    W1B[i - 36864] = f2bf(W1[i - 36864]);
  } else if (i < 69632) {
    W2B[i - 53248] = f2bf(W2[i - 53248]);
  }
}

// ---------------------------------------------------------------------------
// 1) fused accident-scale + graph linear, TRANSPOSED-PACKED output
// ---------------------------------------------------------------------------
__global__ __launch_bounds__(256) void k_lin64T(
    const float* __restrict__ x, const unsigned short* __restrict__ Wb,
    const float* __restrict__ bias, unsigned short* __restrict__ HP) {
  __shared__ unsigned short As[32][36];
  __shared__ unsigned short Bs[64][36];
  const int tid = threadIdx.x;
  const int r0 = blockIdx.x * 32;
  const int w = tid >> 6, l = tid & 63;
  const int rb = (w & 1) * 16, cb = (w >> 1) * 32;
  f32x4 acc0 = {0.f, 0.f, 0.f, 0.f}, acc1 = {0.f, 0.f, 0.f, 0.f};
  const int ar = tid >> 3, ak = (tid & 7) * 4;
  const int bc = tid & 63, bm0 = (tid >> 6) * 4;
  const int k4 = (l >> 4) * 4;
  const int arow = rb + (l & 15);
  const int bcol0 = cb + (l & 15);
  const float* xrow = x + (size_t)(r0 + ar) * 64;
  float sf = 1.0f + 0.3f * xrow[62] * __expf(-xrow[63] * (1.0f / 60.0f));
  for (int k0 = 0; k0 < 64; k0 += 32) {
    __syncthreads();
    float4 xv = *(const float4*)(xrow + k0 + ak);
    ushort4 xb;
    xb.x = f2bf(xv.x * sf); xb.y = f2bf(xv.y * sf);
    xb.z = f2bf(xv.z * sf); xb.w = f2bf(xv.w * sf);
    *(ushort4*)&As[ar][ak] = xb;
#pragma unroll
    for (int j = 0; j < 4; ++j) {
      int mp = bm0 + j;
      unsigned lo = Wb[(size_t)(k0 + 2 * mp) * 64 + bc];
      unsigned hi = Wb[(size_t)(k0 + 2 * mp + 1) * 64 + bc];
      *(unsigned*)&Bs[bc][2 * mp] = lo | (hi << 16);
    }
    __syncthreads();
    s16x4 alo = *(const s16x4*)&As[arow][k4];
    s16x4 ahi = *(const s16x4*)&As[arow][k4 + 16];
    s16x8 a = {alo.x, alo.y, alo.z, alo.w, ahi.x, ahi.y, ahi.z, ahi.w};
    s16x4 b0l = *(const s16x4*)&Bs[bcol0][k4];
    s16x4 b0h = *(const s16x4*)&Bs[bcol0][k4 + 16];
    s16x8 bf0 = {b0l.x, b0l.y, b0l.z, b0l.w, b0h.x, b0h.y, b0h.z, b0h.w};
    s16x4 b1l = *(const s16x4*)&Bs[bcol0 + 16][k4];
    s16x4 b1h = *(const s16x4*)&Bs[bcol0 + 16][k4 + 16];
    s16x8 bf1 = {b1l.x, b1l.y, b1l.z, b1l.w, b1h.x, b1h.y, b1h.z, b1h.w};
    acc0 = __builtin_amdgcn_mfma_f32_16x16x32_bf16(a, bf0, acc0, 0, 0, 0);
    acc1 = __builtin_amdgcn_mfma_f32_16x16x32_bf16(a, bf1, acc1, 0, 0, 0);
  }
  const int c0 = cb + (l & 15);
  float b0 = bias[c0], b1 = bias[c0 + 16];
#pragma unroll
  for (int r = 0; r < 4; ++r) {
    int row = r0 + rb + (l >> 4) * 4 + r;
    int bs = row / NN, m = row % NN;
    HP[((size_t)bs * 64 + c0) * NN + m] = f2bf(acc0[r] + b0);
    HP[((size_t)bs * 64 + c0 + 16) * NN + m] = f2bf(acc1[r] + b1);
  }
}

// ---------------------------------------------------------------------------
// 2) MFMA graph propagation + async-stage split
// ---------------------------------------------------------------------------
template <bool LAST>
__global__ __launch_bounds__(256) void k_prop_mfma(
    const float* __restrict__ adj,
    const unsigned short* __restrict__ HPin,
    const float* __restrict__ x,
    unsigned short* __restrict__ HPout,
    float* __restrict__ pout,
    unsigned short* __restrict__ pbout) {
  __shared__ unsigned short As[32][36];
  __shared__ unsigned short Bs[64][40];
  const int tid = threadIdx.x;
  const int bid = blockIdx.x;
  const int bs = bid / 25, mt = bid % 25;
  const int b = bs / NS;
  const int n0 = mt * 32;
  const float* abase = adj + (size_t)b * NN * NN + (size_t)n0 * NN;
  const unsigned short* hbase = HPin + (size_t)bs * 64 * NN;
  const int w = tid >> 6, l = tid & 63;
  const int rb = (w & 1) * 16;
  const int cb = (w >> 1) * 32;
  f32x4 acc0 = {0.f, 0.f, 0.f, 0.f}, acc1 = {0.f, 0.f, 0.f, 0.f};
  const int ar = tid >> 3, ak = (tid & 7) * 4;
  const int bc = tid & 63, bq = tid >> 6;
  const int k4 = (l >> 4) * 4;
  const int arow = rb + (l & 15);
  const int bcol0 = cb + (l & 15);
  float4 av = *(const float4*)(abase + (size_t)ar * NN + ak);
  s16x8 bv = *(const s16x8*)(hbase + (size_t)bc * NN + bq * 8);
  for (int m0 = 0; m0 < NN; m0 += 32) {
    __syncthreads();
    {
      ushort4 ab;
      ab.x = f2bf(av.x); ab.y = f2bf(av.y);
      ab.z = f2bf(av.z); ab.w = f2bf(av.w);
      *(ushort4*)&As[ar][ak] = ab;
      *(s16x8*)&Bs[bc][bq * 8] = bv;
    }
    __syncthreads();
    if (m0 + 32 < NN) {
      av = *(const float4*)(abase + (size_t)ar * NN + m0 + 32 + ak);
      bv = *(const s16x8*)(hbase + (size_t)bc * NN + m0 + 32 + bq * 8);
    }
    s16x4 alo = *(const s16x4*)&As[arow][k4];
    s16x4 ahi = *(const s16x4*)&As[arow][k4 + 16];
    s16x8 a = {alo.x, alo.y, alo.z, alo.w, ahi.x, ahi.y, ahi.z, ahi.w};
    s16x4 b0l = *(const s16x4*)&Bs[bcol0][k4];
    s16x4 b0h = *(const s16x4*)&Bs[bcol0][k4 + 16];
    s16x8 bf0 = {b0l.x, b0l.y, b0l.z, b0l.w, b0h.x, b0h.y, b0h.z, b0h.w};
    s16x4 b1l = *(const s16x4*)&Bs[bcol0 + 16][k4];
    s16x4 b1h = *(const s16x4*)&Bs[bcol0 + 16][k4 + 16];
    s16x8 bf1 = {b1l.x, b1l.y, b1l.z, b1l.w, b1h.x, b1h.y, b1h.z, b1h.w};
    acc0 = __builtin_amdgcn_mfma_f32_16x16x32_bf16(a, bf0, acc0, 0, 0, 0);
    acc1 = __builtin_amdgcn_mfma_f32_16x16x32_bf16(a, bf1, acc1, 0, 0, 0);
  }
  const int c0 = cb + (l & 15);
  if (LAST) {
#pragma unroll
    for (int r = 0; r < 4; ++r) {
      int n = n0 + rb + (l >> 4) * 4 + r;
      float v0 = fmaxf(acc0[r], 0.f);
      float v1 = fmaxf(acc1[r], 0.f);
      size_t i0 = ((size_t)bs * NN + n) * 64 + c0;
      size_t i1 = i0 + 16;
      float p0 = v0 + x[i0], p1 = v1 + x[i1];
      pout[i0] = p0;
      pout[i1] = p1;
      pbout[i0] = f2bf(p0);
      pbout[i1] = f2bf(p1);
    }
  } else {
    int nb = n0 + rb + (l >> 4) * 4;
    s16x4 o0, o1;
#pragma unroll
    for (int r = 0; r < 4; ++r) {
      o0[r] = (short)f2bf(fmaxf(acc0[r], 0.f));
      o1[r] = (short)f2bf(fmaxf(acc1[r], 0.f));
    }
    *(s16x4*)&HPout[((size_t)bs * 64 + c0) * NN + nb] = o0;
    *(s16x4*)&HPout[((size_t)bs * 64 + c0 + 16) * NN + nb] = o1;
  }
}

// ---------------------------------------------------------------------------
// 3) MFMA fused QKV (bf16 out); Q scaled by qscale (spatial only now)
// ---------------------------------------------------------------------------
__global__ __launch_bounds__(256) void k_qkv_mfma(
    const unsigned short* __restrict__ Xb,
    const unsigned short* __restrict__ Wq,
    const unsigned short* __restrict__ Wk,
    const unsigned short* __restrict__ Wv,
    const float* __restrict__ bq, const float* __restrict__ bk,
    const float* __restrict__ bv, float qscale,
    unsigned short* __restrict__ Qo, unsigned short* __restrict__ Ko,
    unsigned short* __restrict__ Vo) {
  __shared__ unsigned short As[32][36];
  __shared__ unsigned short Bs[3][64][36];
  const int tid = threadIdx.x;
  const int r0 = blockIdx.x * 32;
  const int w = tid >> 6, l = tid & 63;
  const int rb = (w & 1) * 16;
  const int cb = (w >> 1) * 32;
  f32x4 acc[3][2];
#pragma unroll
  for (int i = 0; i < 3; ++i)
#pragma unroll
    for (int j = 0; j < 2; ++j) acc[i][j] = (f32x4){0.f, 0.f, 0.f, 0.f};
  const unsigned short* Wm[3] = {Wq, Wk, Wv};
  const int ar = tid >> 3, ak = (tid & 7) * 4;
  const int bc = tid & 63, bm0 = (tid >> 6) * 4;
  const int k4 = (l >> 4) * 4;
  const int arow = rb + (l & 15);
  const int bcol0 = cb + (l & 15);
  for (int k0 = 0; k0 < 64; k0 += 32) {
    __syncthreads();
    *(s16x4*)&As[ar][ak] =
        *(const s16x4*)(Xb + (size_t)(r0 + ar) * 64 + k0 + ak);
#pragma unroll
    for (int wm = 0; wm < 3; ++wm) {
#pragma unroll
      for (int j = 0; j < 4; ++j) {
        int mp = bm0 + j;
        unsigned lo = Wm[wm][(size_t)(k0 + 2 * mp) * 64 + bc];
        unsigned hi = Wm[wm][(size_t)(k0 + 2 * mp + 1) * 64 + bc];
        *(unsigned*)&Bs[wm][bc][2 * mp] = lo | (hi << 16);
      }
    }
    __syncthreads();
    s16x4 alo = *(const s16x4*)&As[arow][k4];
    s16x4 ahi = *(const s16x4*)&As[arow][k4 + 16];
    s16x8 a = {alo.x, alo.y, alo.z, alo.w, ahi.x, ahi.y, ahi.z, ahi.w};
#pragma unroll
    for (int wm = 0; wm < 3; ++wm) {
      s16x4 b0l = *(const s16x4*)&Bs[wm][bcol0][k4];
      s16x4 b0h = *(const s16x4*)&Bs[wm][bcol0][k4 + 16];
      s16x8 bf0 = {b0l.x, b0l.y, b0l.z, b0l.w, b0h.x, b0h.y, b0h.z, b0h.w};
      s16x4 b1l = *(const s16x4*)&Bs[wm][bcol0 + 16][k4];
      s16x4 b1h = *(const s16x4*)&Bs[wm][bcol0 + 16][k4 + 16];
      s16x8 bf1 = {b1l.x, b1l.y, b1l.z, b1l.w, b1h.x, b1h.y, b1h.z, b1h.w};
      acc[wm][0] = __builtin_amdgcn_mfma_f32_16x16x32_bf16(a, bf0, acc[wm][0], 0, 0, 0);
      acc[wm][1] = __builtin_amdgcn_mfma_f32_16x16x32_bf16(a, bf1, acc[wm][1], 0, 0, 0);
    }
  }
  const float* bm[3] = {bq, bk, bv};
  unsigned short* Om[3] = {Qo, Ko, Vo};
  const int c0 = cb + (l & 15);
#pragma unroll
  for (int wm = 0; wm < 3; ++wm) {
    float b0 = bm[wm][c0], b1 = bm[wm][c0 + 16];
    float sc = (wm == 0) ? qscale : 1.0f;
#pragma unroll
    for (int r = 0; r < 4; ++r) {
      int row = r0 + rb + (l >> 4) * 4 + r;
      Om[wm][(size_t)row * 64 + c0] = f2bf((acc[wm][0][r] + b0) * sc);
      Om[wm][(size_t)row * 64 + c0 + 16] = f2bf((acc[wm][1][r] + b1) * sc);
    }
  }
}

// ---------------------------------------------------------------------------
// 4) spatial attention v5: fixed-max flash + unroll-5 tile pipeline.
// ---------------------------------------------------------------------------
__global__ __launch_bounds__(256) void k_sattn5(
    const unsigned short* __restrict__ Qb,
    const unsigned short* __restrict__ Kb,
    const unsigned short* __restrict__ Vb,
    unsigned short* __restrict__ OB) {
  __shared__ unsigned short Ks[800][8];
  __shared__ unsigned short Vt[25 * 256 + 256];
  const int bs = blockIdx.x, h = blockIdx.y;
  const int tid = threadIdx.x;
  const size_t base = (size_t)bs * NN * 64 + h * DH;
  for (int r = tid; r < NN; r += 256)
    *(s16x8*)&Ks[r][0] = *(const s16x8*)(Kb + base + (size_t)r * 64);
  if (tid < 200) {
    int t = tid >> 3, c = tid & 7;
    int r = t * 32 + c * 4;
    s16x8 v0 = *(const s16x8*)(Vb + base + (size_t)r * 64);
    s16x8 v1 = *(const s16x8*)(Vb + base + (size_t)(r + 1) * 64);
    s16x8 v2 = *(const s16x8*)(Vb + base + (size_t)(r + 2) * 64);
    s16x8 v3 = *(const s16x8*)(Vb + base + (size_t)(r + 3) * 64);
#pragma unroll
    for (int d = 0; d < 8; ++d) {
      unsigned lo = (unsigned short)v0[d] | ((unsigned)(unsigned short)v1[d] << 16);
      unsigned hi = (unsigned short)v2[d] | ((unsigned)(unsigned short)v3[d] << 16);
      unsigned* dst = (unsigned*)&Vt[t * 256 + d * 32 + ((c ^ d) & 7) * 4];
      dst[0] = lo;
      dst[1] = hi;
    }
  }
  __syncthreads();
  const int w = tid >> 6, l = tid & 63;
  const int q0 = blockIdx.z * 128 + w * 32;
  if (q0 >= NN) return;
  const int r15 = l & 15, g = l >> 4;
  const int dd = r15;
  const int off1 = dd * 32 + ((g ^ dd) & 7) * 4;
  const int off2 = dd * 32 + (((4 + g) ^ dd) & 7) * 4;
  s16x4 qvA = *(const s16x4*)(Qb + base + (size_t)(q0 + r15) * 64 + (g & 1) * 4);
  s16x4 qvB = *(const s16x4*)(Qb + base + (size_t)(q0 + 16 + r15) * 64 + (g & 1) * 4);
  s16x8 qfA = {0, 0, 0, 0, 0, 0, 0, 0};
  s16x8 qfB = {0, 0, 0, 0, 0, 0, 0, 0};
  if (g < 2) {
    qfA[0] = qvA.x; qfA[1] = qvA.y; qfA[2] = qvA.z; qfA[3] = qvA.w;
    qfB[0] = qvB.x; qfB[1] = qvB.y; qfB[2] = qvB.z; qfB[3] = qvB.w;
  }
  const short one_bf = (short)0x3F80;
  f32x4 accA = {0.f, 0.f, 0.f, 0.f}, accB = {0.f, 0.f, 0.f, 0.f};
  const f32x4 zero4 = {0.f, 0.f, 0.f, 0.f};
#pragma unroll 5
  for (int t = 0; t < 25; ++t) {
    s16x4 ka = *(const s16x4*)&Ks[t * 32 + r15][(g & 1) * 4];
    s16x4 kb = *(const s16x4*)&Ks[t * 32 + 16 + r15][(g & 1) * 4];
    s16x8 kfa = {0, 0, 0, 0, 0, 0, 0, 0};
    s16x8 kfb = {0, 0, 0, 0, 0, 0, 0, 0};
    if (g < 2) {
      kfa[0] = ka.x; kfa[1] = ka.y; kfa[2] = ka.z; kfa[3] = ka.w;
      kfb[0] = kb.x; kfb[1] = kb.y; kfb[2] = kb.z; kfb[3] = kb.w;
    }
    s16x4 va = *(const s16x4*)&Vt[t * 256 + off1];
    s16x4 vb = *(const s16x4*)&Vt[t * 256 + off2];
    s16x8 vf;
    if (dd < 8) {
      vf = (s16x8){va.x, va.y, va.z, va.w, vb.x, vb.y, vb.z, vb.w};
    } else if (dd == 8) {
      vf = (s16x8){one_bf, one_bf, one_bf, one_bf, one_bf, one_bf, one_bf, one_bf};
    } else {
      vf = (s16x8){0, 0, 0, 0, 0, 0, 0, 0};
    }
    f32x4 sA1 = __builtin_amdgcn_mfma_f32_16x16x32_bf16(kfa, qfA, zero4, 0, 0, 0);
    f32x4 sA2 = __builtin_amdgcn_mfma_f32_16x16x32_bf16(kfb, qfA, zero4, 0, 0, 0);
    f32x4 sB1 = __builtin_amdgcn_mfma_f32_16x16x32_bf16(kfa, qfB, zero4, 0, 0, 0);
    f32x4 sB2 = __builtin_amdgcn_mfma_f32_16x16x32_bf16(kfb, qfB, zero4, 0, 0, 0);
    float pA[8], pB[8];
#pragma unroll
    for (int r = 0; r < 4; ++r) {
      pA[r] = fexp2(sA1[r]);
      pA[4 + r] = fexp2(sA2[r]);
      pB[r] = fexp2(sB1[r]);
      pB[4 + r] = fexp2(sB2[r]);
    }
    union { unsigned u[4]; s16x8 v; } puA, puB;
    puA.u[0] = cvtpk_bf16(pA[0], pA[1]);
    puA.u[1] = cvtpk_bf16(pA[2], pA[3]);
    puA.u[2] = cvtpk_bf16(pA[4], pA[5]);
    puA.u[3] = cvtpk_bf16(pA[6], pA[7]);
    puB.u[0] = cvtpk_bf16(pB[0], pB[1]);
    puB.u[1] = cvtpk_bf16(pB[2], pB[3]);
    puB.u[2] = cvtpk_bf16(pB[4], pB[5]);
    puB.u[3] = cvtpk_bf16(pB[6], pB[7]);
    accA = __builtin_amdgcn_mfma_f32_16x16x32_bf16(vf, puA.v, accA, 0, 0, 0);
    accB = __builtin_amdgcn_mfma_f32_16x16x32_bf16(vf, puB.v, accB, 0, 0, 0);
  }
  float lsA = __shfl(accA[0], 32 + r15, 64);
  float lsB = __shfl(accB[0], 32 + r15, 64);
  float invA = 1.f / lsA;
  float invB = 1.f / lsB;
  if (g < 2) {
#pragma unroll
    for (int r = 0; r < 4; ++r) {
      int d = g * 4 + r;
      OB[base + (size_t)(q0 + r15) * 64 + d] = f2bf(accA[r] * invA);
      OB[base + (size_t)(q0 + 16 + r15) * 64 + d] = f2bf(accB[r] * invB);
    }
  }
}

// ---------------------------------------------------------------------------
// 5) FUSED: spatial proj + residual + LN  ->  temporal QKV (LDS hand-off)
//    Aout (f32) = LN(OBuf@Wo_s + bo_s + P)   [residual for temporal projln]
//    {Q2,K2,V2} = bf16( LN_out @ W{q,k,v}_t + b )
// ---------------------------------------------------------------------------
__global__ __launch_bounds__(256) void k_sproj_tqkv(
    const unsigned short* __restrict__ OBuf,
    const unsigned short* __restrict__ WoS, const float* __restrict__ boS,
    const float* __restrict__ res, const float* __restrict__ gS,
    const float* __restrict__ beS,
    const unsigned short* __restrict__ Wq,
    const unsigned short* __restrict__ Wk,
    const unsigned short* __restrict__ Wv,
    const float* __restrict__ bq, const float* __restrict__ bk,
    const float* __restrict__ bv,
    float* __restrict__ Aout, unsigned short* __restrict__ Qo,
    unsigned short* __restrict__ Ko, unsigned short* __restrict__ Vo) {
  __shared__ unsigned short Xs[32][68];
  __shared__ unsigned short Bs[64][68];
  __shared__ float CT[32][68];
  const int tid = threadIdx.x;
  const int r0 = blockIdx.x * 32;
  const int w = tid >> 6, l = tid & 63;
  const int rb = (w & 1) * 16, cb = (w >> 1) * 32;
  const int r15 = l & 15;
  const int k4 = (l >> 4) * 4;
  const int arow = rb + r15;
  const int bcol0 = cb + r15;
  const int c0 = cb + r15;
  // stage Xs <- OBuf rows; Bs <- WoS full-K
  {
    int ar = tid >> 3, ak8 = (tid & 7) * 8;
    *(s16x8*)&Xs[ar][ak8] = *(const s16x8*)(OBuf + (size_t)(r0 + ar) * 64 + ak8);
    int bc = tid & 63, bm0 = (tid >> 6) * 8;
#pragma unroll
    for (int j = 0; j < 8; ++j) {
      int mp = bm0 + j;
      unsigned lo = WoS[(size_t)(2 * mp) * 64 + bc];
      unsigned hi = WoS[(size_t)(2 * mp + 1) * 64 + bc];
      *(unsigned*)&Bs[bc][2 * mp] = lo | (hi << 16);
    }
  }
  __syncthreads();
  // proj MFMA (K=64)
  f32x4 acc0 = {0.f, 0.f, 0.f, 0.f}, acc1 = {0.f, 0.f, 0.f, 0.f};
#pragma unroll
  for (int k0 = 0; k0 < 64; k0 += 32) {
    s16x4 alo = *(const s16x4*)&Xs[arow][k0 + k4];
    s16x4 ahi = *(const s16x4*)&Xs[arow][k0 + k4 + 16];
    s16x8 a = {alo.x, alo.y, alo.z, alo.w, ahi.x, ahi.y, ahi.z, ahi.w};
    s16x4 b0l = *(const s16x4*)&Bs[bcol0][k0 + k4];
    s16x4 b0h = *(const s16x4*)&Bs[bcol0][k0 + k4 + 16];
    s16x8 bf0 = {b0l.x, b0l.y, b0l.z, b0l.w, b0h.x, b0h.y, b0h.z, b0h.w};
    s16x4 b1l = *(const s16x4*)&Bs[bcol0 + 16][k0 + k4];
    s16x4 b1h = *(const s16x4*)&Bs[bcol0 + 16][k0 + k4 + 16];
    s16x8 bf1 = {b1l.x, b1l.y, b1l.z, b1l.w, b1h.x, b1h.y, b1h.z, b1h.w};
    acc0 = __builtin_amdgcn_mfma_f32_16x16x32_bf16(a, bf0, acc0, 0, 0, 0);
    acc1 = __builtin_amdgcn_mfma_f32_16x16x32_bf16(a, bf1, acc1, 0, 0, 0);
  }
#pragma unroll
  for (int r = 0; r < 4; ++r) {
    int row = rb + (l >> 4) * 4 + r;
    size_t gi = (size_t)(r0 + row) * 64;
    CT[row][c0] = acc0[r] + boS[c0] + res[gi + c0];
    CT[row][c0 + 16] = acc1[r] + boS[c0 + 16] + res[gi + c0 + 16];
  }
  __syncthreads();
  // LN (8 elems/thread); write Aout f32 + Xs bf16 (overwrite)
  {
    const int row = tid >> 3, sub = tid & 7;
    float v[8];
#pragma unroll
    for (int i = 0; i < 8; ++i) v[i] = CT[row][sub * 8 + i];
    float s = 0.f;
#pragma unroll
    for (int i = 0; i < 8; ++i) s += v[i];
#pragma unroll
    for (int off = 1; off < 8; off <<= 1) s += __shfl_xor(s, off, 64);
    float mean = s * (1.f / 64.f);
    float q = 0.f;
#pragma unroll
    for (int i = 0; i < 8; ++i) {
      float d = v[i] - mean;
      q += d * d;
    }
#pragma unroll
    for (int off = 1; off < 8; off <<= 1) q += __shfl_xor(q, off, 64);
    float rstd = rsqrtf(q * (1.f / 64.f) + 1e-5f);
    float r4[8];
#pragma unroll
    for (int i = 0; i < 8; ++i)
      r4[i] = (v[i] - mean) * rstd * gS[sub * 8 + i] + beS[sub * 8 + i];
    float* op = Aout + (size_t)(r0 + row) * 64 + sub * 8;
    *(float4*)op = (float4){r4[0], r4[1], r4[2], r4[3]};
    *(float4*)(op + 4) = (float4){r4[4], r4[5], r4[6], r4[7]};
#pragma unroll
    for (int i = 0; i < 8; ++i) Xs[row][sub * 8 + i] = f2bf(r4[i]);
  }
  // phase 2: temporal QKV from Xs
  const unsigned short* Wm[3] = {Wq, Wk, Wv};
  const float* bm[3] = {bq, bk, bv};
  unsigned short* Om[3] = {Qo, Ko, Vo};
#pragma unroll 1
  for (int wm = 0; wm < 3; ++wm) {
    __syncthreads();
    {
      int bc = tid & 63, bm0 = (tid >> 6) * 8;
#pragma unroll
      for (int j = 0; j < 8; ++j) {
        int mp = bm0 + j;
        unsigned lo = Wm[wm][(size_t)(2 * mp) * 64 + bc];
        unsigned hi = Wm[wm][(size_t)(2 * mp + 1) * 64 + bc];
        *(unsigned*)&Bs[bc][2 * mp] = lo | (hi << 16);
      }
    }
    __syncthreads();
    f32x4 q0a = {0.f, 0.f, 0.f, 0.f}, q1a = {0.f, 0.f, 0.f, 0.f};
#pragma unroll
    for (int k0 = 0; k0 < 64; k0 += 32) {
      s16x4 alo = *(const s16x4*)&Xs[arow][k0 + k4];
      s16x4 ahi = *(const s16x4*)&Xs[arow][k0 + k4 + 16];
      s16x8 a = {alo.x, alo.y, alo.z, alo.w, ahi.x, ahi.y, ahi.z, ahi.w};
      s16x4 b0l = *(const s16x4*)&Bs[bcol0][k0 + k4];
      s16x4 b0h = *(const s16x4*)&Bs[bcol0][k0 + k4 + 16];
      s16x8 bf0 = {b0l.x, b0l.y, b0l.z, b0l.w, b0h.x, b0h.y, b0h.z, b0h.w};
      s16x4 b1l = *(const s16x4*)&Bs[bcol0 + 16][k0 + k4];
      s16x4 b1h = *(const s16x4*)&Bs[bcol0 + 16][k0 + k4 + 16];
      s16x8 bf1 = {b1l.x, b1l.y, b1l.z, b1l.w, b1h.x, b1h.y, b1h.z, b1h.w};
      q0a = __builtin_amdgcn_mfma_f32_16x16x32_bf16(a, bf0, q0a, 0, 0, 0);
      q1a = __builtin_amdgcn_mfma_f32_16x16x32_bf16(a, bf1, q1a, 0, 0, 0);
    }
    float b0 = bm[wm][c0], b1 = bm[wm][c0 + 16];
#pragma unroll
    for (int r = 0; r < 4; ++r) {
      int row = r0 + rb + (l >> 4) * 4 + r;
      Om[wm][(size_t)row * 64 + c0] = f2bf(q0a[r] + b0);
      Om[wm][(size_t)row * 64 + c0 + 16] = f2bf(q1a[r] + b1);
    }
  }
}

// ---------------------------------------------------------------------------
// 6) temporal attention: one block per (b,n), L = 12; bf16 in/out
// ---------------------------------------------------------------------------
__global__ __launch_bounds__(256) void k_tattn(
    const unsigned short* __restrict__ Q, const unsigned short* __restrict__ K,
    const unsigned short* __restrict__ V, unsigned short* __restrict__ O) {
  int b = blockIdx.x / NN, n = blockIdx.x % NN;
  __shared__ float Qs[12][64], Ks[12][64], Vs[12][64];
  int tid = threadIdx.x;
  for (int i = tid; i < 12 * 64; i += 256) {
    int s = i >> 6, c = i & 63;
    size_t idx = (((size_t)b * NS + s) * NN + n) * 64 + c;
    Qs[s][c] = bf2f(Q[idx]);
    Ks[s][c] = bf2f(K[idx]);
    Vs[s][c] = bf2f(V[idx]);
  }
  __syncthreads();
  for (int wi = tid; wi < 12 * 64; wi += 256) {
    int l = wi >> 6, c = wi & 63;
    int h8 = c & 56;
    float sc[12];
    float mx = -1e30f;
#pragma unroll
    for (int m = 0; m < 12; ++m) {
      float s = 0.f;
#pragma unroll
      for (int d = 0; d < 8; ++d) s += Qs[l][h8 + d] * Ks[m][h8 + d];
      s *= 0.35355339059327373f;
      sc[m] = s;
      mx = fmaxf(mx, s);
    }
    float sum = 0.f;
#pragma unroll
    for (int m = 0; m < 12; ++m) {
      sc[m] = __expf(sc[m] - mx);
      sum += sc[m];
    }
    float inv = 1.f / sum;
    float o = 0.f;
#pragma unroll
    for (int m = 0; m < 12; ++m) o += sc[m] * Vs[m][c];
    size_t idx = (((size_t)b * NS + l) * NN + n) * 64 + c;
    O[idx] = f2bf(o * inv);
  }
}

// ---------------------------------------------------------------------------
// 7) FUSED: temporal proj + LN_t + LN1 + FFN1 + FFN2 + residual + final LN
// ---------------------------------------------------------------------------
__global__ __launch_bounds__(256) void k_tproj_ffn(
    const unsigned short* __restrict__ TBin,
    const unsigned short* __restrict__ WoT, const float* __restrict__ boT,
    const float* __restrict__ resA, const float* __restrict__ gT,
    const float* __restrict__ beT, const float* __restrict__ g1,
    const float* __restrict__ be1,
    const unsigned short* __restrict__ W1b, const float* __restrict__ b1,
    const unsigned short* __restrict__ W2b, const float* __restrict__ b2,
    const float* __restrict__ g2, const float* __restrict__ be2,
    float* __restrict__ out) {
  __shared__ unsigned short Xs[32][68];
  __shared__ unsigned short Bs[64][68];
  __shared__ float CT[32][68];
  __shared__ unsigned short Hs[32][264];
  const int tid = threadIdx.x;
  const int r0 = blockIdx.x * 32;
  const int w = tid >> 6, l = tid & 63;
  const int rb = (w & 1) * 16, cb = (w >> 1) * 32;
  const int r15 = l & 15;
  const int k4 = (l >> 4) * 4;
  const int arow = rb + r15;
  const int bcol0 = cb + r15;
  const int c0 = cb + r15;
  const int sbc = tid & 63;
  // stage Xs <- TB; Bs <- WoT full-K
  {
    int ar = tid >> 3, ak8 = (tid & 7) * 8;
    *(s16x8*)&Xs[ar][ak8] = *(const s16x8*)(TBin + (size_t)(r0 + ar) * 64 + ak8);
    int bm0 = (tid >> 6) * 8;
#pragma unroll
    for (int j = 0; j < 8; ++j) {
      int mp = bm0 + j;
      unsigned lo = WoT[(size_t)(2 * mp) * 64 + sbc];
      unsigned hi = WoT[(size_t)(2 * mp + 1) * 64 + sbc];
      *(unsigned*)&Bs[sbc][2 * mp] = lo | (hi << 16);
    }
  }
  __syncthreads();
  // proj MFMA (K=64)
  {
    f32x4 acc0 = {0.f, 0.f, 0.f, 0.f}, acc1 = {0.f, 0.f, 0.f, 0.f};
#pragma unroll
    for (int k0 = 0; k0 < 64; k0 += 32) {
      s16x4 alo = *(const s16x4*)&Xs[arow][k0 + k4];
      s16x4 ahi = *(const s16x4*)&Xs[arow][k0 + k4 + 16];
      s16x8 a = {alo.x, alo.y, alo.z, alo.w, ahi.x, ahi.y, ahi.z, ahi.w};
      s16x4 b0l = *(const s16x4*)&Bs[bcol0][k0 + k4];
      s16x4 b0h = *(const s16x4*)&Bs[bcol0][k0 + k4 + 16];
      s16x8 bf0 = {b0l.x, b0l.y, b0l.z, b0l.w, b0h.x, b0h.y, b0h.z, b0h.w};
      s16x4 b1l = *(const s16x4*)&Bs[bcol0 + 16][k0 + k4];
      s16x4 b1h = *(const s16x4*)&Bs[bcol0 + 16][k0 + k4 + 16];
      s16x8 bf1 = {b1l.x, b1l.y, b1l.z, b1l.w, b1h.x, b1h.y, b1h.z, b1h.w};
      acc0 = __builtin_amdgcn_mfma_f32_16x16x32_bf16(a, bf0, acc0, 0, 0, 0);
      acc1 = __builtin_amdgcn_mfma_f32_16x16x32_bf16(a, bf1, acc1, 0, 0, 0);
    }
#pragma unroll
    for (int r = 0; r < 4; ++r) {
      int row = rb + (l >> 4) * 4 + r;
      size_t gi = (size_t)(r0 + row) * 64;
      CT[row][c0] = acc0[r] + boT[c0] + resA[gi + c0];
      CT[row][c0 + 16] = acc1[r] + boT[c0 + 16] + resA[gi + c0 + 16];
    }
  }
  __syncthreads();
  // LN_t -> attn_out (back into CT) ; LN1 -> Xs (bf16)
  {
    const int row = tid >> 3, sub = tid & 7;
    float v[8];
#pragma unroll
    for (int i = 0; i < 8; ++i) v[i] = CT[row][sub * 8 + i];
    float s = 0.f;
#pragma unroll
    for (int i = 0; i < 8; ++i) s += v[i];
#pragma unroll
    for (int off = 1; off < 8; off <<= 1) s += __shfl_xor(s, off, 64);
    float mean = s * (1.f / 64.f);
    float q = 0.f;
#pragma unroll
    for (int i = 0; i < 8; ++i) {
      float d = v[i] - mean;
      q += d * d;
    }
#pragma unroll
    for (int off = 1; off < 8; off <<= 1) q += __shfl_xor(q, off, 64);
    float rstd = rsqrtf(q * (1.f / 64.f) + 1e-5f);
    float r4[8];
#pragma unroll
    for (int i = 0; i < 8; ++i)
      r4[i] = (v[i] - mean) * rstd * gT[sub * 8 + i] + beT[sub * 8 + i];
#pragma unroll
    for (int i = 0; i < 8; ++i) CT[row][sub * 8 + i] = r4[i];
    // LN1 over r4
    float s2 = 0.f;
#pragma unroll
    for (int i = 0; i < 8; ++i) s2 += r4[i];
#pragma unroll
    for (int off = 1; off < 8; off <<= 1) s2 += __shfl_xor(s2, off, 64);
    float mean2 = s2 * (1.f / 64.f);
    float q2 = 0.f;
#pragma unroll
    for (int i = 0; i < 8; ++i) {
      float d2 = r4[i] - mean2;
      q2 += d2 * d2;
    }
#pragma unroll
    for (int off = 1; off < 8; off <<= 1) q2 += __shfl_xor(q2, off, 64);
    float rstd2 = rsqrtf(q2 * (1.f / 64.f) + 1e-5f);
#pragma unroll
    for (int i = 0; i < 8; ++i)
      Xs[row][sub * 8 + i] =
          f2bf((r4[i] - mean2) * rstd2 * g1[sub * 8 + i] + be1[sub * 8 + i]);
  }
  __syncthreads();
  // FFN1: hid = relu(Xs @ W1 + b1) -> Hs, 4 column chunks of 64
  for (int c = 0; c < 4; ++c) {
    {
      const int bm0 = (tid >> 6) * 8;
      int gcol = c * 64 + sbc;
#pragma unroll
      for (int j = 0; j < 8; ++j) {
        int mp = bm0 + j;
        unsigned lo = W1b[(size_t)(2 * mp) * 256 + gcol];
        unsigned hi = W1b[(size_t)(2 * mp + 1) * 256 + gcol];
        *(unsigned*)&Bs[sbc][2 * mp] = lo | (hi << 16);
      }
    }
    __syncthreads();
    f32x4 acc0 = {0.f, 0.f, 0.f, 0.f}, acc1 = {0.f, 0.f, 0.f, 0.f};
#pragma unroll
    for (int k0 = 0; k0 < 64; k0 += 32) {
      s16x4 alo = *(const s16x4*)&Xs[arow][k0 + k4];
      s16x4 ahi = *(const s16x4*)&Xs[arow][k0 + k4 + 16];
      s16x8 a = {alo.x, alo.y, alo.z, alo.w, ahi.x, ahi.y, ahi.z, ahi.w};
      s16x4 b0l = *(const s16x4*)&Bs[bcol0][k0 + k4];
      s16x4 b0h = *(const s16x4*)&Bs[bcol0][k0 + k4 + 16];
      s16x8 bf0 = {b0l.x, b0l.y, b0l.z, b0l.w, b0h.x, b0h.y, b0h.z, b0h.w};
      s16x4 b1l = *(const s16x4*)&Bs[bcol0 + 16][k0 + k4];
      s16x4 b1h = *(const s16x4*)&Bs[bcol0 + 16][k0 + k4 + 16];
      s16x8 bf1 = {b1l.x, b1l.y, b1l.z, b1l.w, b1h.x, b1h.y, b1h.z, b1h.w};
      acc0 = __builtin_amdgcn_mfma_f32_16x16x32_bf16(a, bf0, acc0, 0, 0, 0);
      acc1 = __builtin_amdgcn_mfma_f32_16x16x32_bf16(a, bf1, acc1, 0, 0, 0);
    }
    float bb0 = b1[c * 64 + c0], bb1v = b1[c * 64 + c0 + 16];
#pragma unroll
    for (int r = 0; r < 4; ++r) {
      int row = rb + (l >> 4) * 4 + r;
      Hs[row][c * 64 + c0] = f2bf(fmaxf(acc0[r] + bb0, 0.f));
      Hs[row][c * 64 + c0 + 16] = f2bf(fmaxf(acc1[r] + bb1v, 0.f));
    }
    __syncthreads();
  }
  // FFN2: acc = Hs @ W2 (K=256, 8 chunks)
  f32x4 acc0 = {0.f, 0.f, 0.f, 0.f}, acc1 = {0.f, 0.f, 0.f, 0.f};
  const int smp4 = (tid >> 6) * 4;
  for (int k0 = 0; k0 < 256; k0 += 32) {
#pragma unroll
    for (int j = 0; j < 4; ++j) {
      int mp = smp4 + j;
      unsigned lo = W2b[(size_t)(k0 + 2 * mp) * 64 + sbc];
      unsigned hi = W2b[(size_t)(k0 + 2 * mp + 1) * 64 + sbc];
      *(unsigned*)&Bs[sbc][2 * mp] = lo | (hi << 16);
    }
    __syncthreads();
    s16x4 alo = *(const s16x4*)&Hs[arow][k0 + k4];
    s16x4 ahi = *(const s16x4*)&Hs[arow][k0 + k4 + 16];
    s16x8 a = {alo.x, alo.y, alo.z, alo.w, ahi.x, ahi.y, ahi.z, ahi.w};
    s16x4 b0l = *(const s16x4*)&Bs[bcol0][k4];
    s16x4 b0h = *(const s16x4*)&Bs[bcol0][k4 + 16];
    s16x8 bf0 = {b0l.x, b0l.y, b0l.z, b0l.w, b0h.x, b0h.y, b0h.z, b0h.w};
    s16x4 b1l = *(const s16x4*)&Bs[bcol0 + 16][k4];
    s16x4 b1h = *(const s16x4*)&Bs[bcol0 + 16][k4 + 16];
    s16x8 bf1 = {b1l.x, b1l.y, b1l.z, b1l.w, b1h.x, b1h.y, b1h.z, b1h.w};
    acc0 = __builtin_amdgcn_mfma_f32_16x16x32_bf16(a, bf0, acc0, 0, 0, 0);
    acc1 = __builtin_amdgcn_mfma_f32_16x16x32_bf16(a, bf1, acc1, 0, 0, 0);
    __syncthreads();
  }
  // epilogue: + b2 + attn_out (CT in-place), then final LN -> out
#pragma unroll
  for (int r = 0; r < 4; ++r) {
    int row = rb + (l >> 4) * 4 + r;
    CT[row][c0] = acc0[r] + b2[c0] + CT[row][c0];
    CT[row][c0 + 16] = acc1[r] + b2[c0 + 16] + CT[row][c0 + 16];
  }
  __syncthreads();
  {
    const int row = tid >> 3, sub = tid & 7;
    float v[8];
#pragma unroll
    for (int i = 0; i < 8; ++i) v[i] = CT[row][sub * 8 + i];
    float s = 0.f;
#pragma unroll
    for (int i = 0; i < 8; ++i) s += v[i];
#pragma unroll
    for (int off = 1; off < 8; off <<= 1) s += __shfl_xor(s, off, 64);
    float mean = s * (1.f / 64.f);
    float q = 0.f;
#pragma unroll
    for (int i = 0; i < 8; ++i) {
      float d = v[i] - mean;
      q += d * d;
    }
#pragma unroll
    for (int off = 1; off < 8; off <<= 1) q += __shfl_xor(q, off, 64);
    float rstd = rsqrtf(q * (1.f / 64.f) + 1e-5f);
    float r4[8];
#pragma unroll
    for (int i = 0; i < 8; ++i)
      r4[i] = (v[i] - mean) * rstd * g2[sub * 8 + i] + be2[sub * 8 + i];
    float* op = out + (size_t)(r0 + row) * 64 + sub * 8;
    *(float4*)op = (float4){r4[0], r4[1], r4[2], r4[3]};
    *(float4*)(op + 4) = (float4){r4[4], r4[5], r4[6], r4[7]};
  }
}

// ---------------------------------------------------------------------------
extern "C" void kernel_launch(void* const* d_in, const int* in_sizes, int n_in,
                              void* d_out, int out_size, void* d_ws,
                              size_t ws_size, hipStream_t stream) {
  const float* x = (const float*)d_in[0];
  const float* adj = (const float*)d_in[1];
  const float* W_gp = (const float*)d_in[2];
  const float* b_gp = (const float*)d_in[3];
  const float* Wq_s = (const float*)d_in[4];
  const float* Wk_s = (const float*)d_in[5];
  const float* Wv_s = (const float*)d_in[6];
  const float* Wo_s = (const float*)d_in[7];
  const float* bq_s = (const float*)d_in[8];
  const float* bk_s = (const float*)d_in[9];
  const float* bv_s = (const float*)d_in[10];
  const float* bo_s = (const float*)d_in[11];
  const float* g_s = (const float*)d_in[12];
  const float* be_s = (const float*)d_in[13];
  const float* Wq_t = (const float*)d_in[14];
  const float* Wk_t = (const float*)d_in[15];
  const float* Wv_t = (const float*)d_in[16];
  const float* Wo_t = (const float*)d_in[17];
  const float* bq_t = (const float*)d_in[18];
  const float* bk_t = (const float*)d_in[19];
  const float* bv_t = (const float*)d_in[20];
  const float* bo_t = (const float*)d_in[21];
  const float* g_t = (const float*)d_in[22];
  const float* be_t = (const float*)d_in[23];
  const float* W1 = (const float*)d_in[24];
  const float* b1 = (const float*)d_in[25];
  const float* W2 = (const float*)d_in[26];
  const float* b2 = (const float*)d_in[27];
  const float* g1 = (const float*)d_in[28];
  const float* be1 = (const float*)d_in[29];
  const float* g2 = (const float*)d_in[30];
  const float* be2 = (const float*)d_in[31];
  float* out = (float*)d_out;

  float* ws = (float*)d_ws;
  const size_t U = (size_t)NR * 64;  // 1,228,800 floats
  float* A = ws + 0 * U;             // spatial-LN output (f32)
  float* P = ws + 4 * U;             // prop residual output (f32)
  // bf16 overlays
  unsigned short* QB = (unsigned short*)(ws + 0 * U);  // spatial Q (pre-A)
  unsigned short* KB = (unsigned short*)(ws + 1 * U);  // spatial K
  unsigned short* VB = (unsigned short*)(ws + 2 * U);  // spatial V
  unsigned short* OBuf = (unsigned short*)(ws + 3 * U);  // sattn out
  unsigned short* Q2 = (unsigned short*)(ws + 1 * U);    // temporal Q
  unsigned short* K2 = (unsigned short*)(ws + 6 * U);
  unsigned short* V2 = K2 + (size_t)NR * 64;
  unsigned short* PB = (unsigned short*)(ws + 5 * U);  // prop out bf16
  unsigned short* TB = (unsigned short*)(ws + 7 * U);  // tattn out bf16
  unsigned short* W1B = (unsigned short*)(ws + 7 * U + U / 2);
  unsigned short* W2B = W1B + 16384;
  unsigned short* HP0 = (unsigned short*)(ws + 9 * U);
  unsigned short* HP1 = (unsigned short*)(ws + 9 * U + U / 2);
  unsigned short* WB = (unsigned short*)(ws + 10 * U + 650240);  // 9*4096 sh

  dim3 blk(256);
  // 0) all weight conversions (one launch)
  k_wconv<<<272, blk, 0, stream>>>(Wq_s, Wk_s, Wv_s, Wq_t, Wk_t, Wv_t, W_gp,
                                   Wo_s, Wo_t, W1, W2, WB, W1B, W2B);
  // 1) fused accident-scale + graph linear -> HP0 (transposed-packed bf16)
  k_lin64T<<<NR / 32, blk, 0, stream>>>(x, WB + 6 * 4096, b_gp, HP0);
  // 2) 3 MFMA propagation steps (async-stage split)
  k_prop_mfma<false><<<NBS * 25, blk, 0, stream>>>(adj, HP0, x, HP1, P, PB);
  k_prop_mfma<false><<<NBS * 25, blk, 0, stream>>>(adj, HP1, x, HP0, P, PB);
  k_prop_mfma<true><<<NBS * 25, blk, 0, stream>>>(adj, HP0, x, HP1, P, PB);
  // 3) spatial: QKV (Q pre-scaled) -> sattn5 -> OBuf
  k_qkv_mfma<<<NR / 32, blk, 0, stream>>>(PB, WB, WB + 4096, WB + 8192, bq_s,
                                          bk_s, bv_s, SC_LOG2, QB, KB, VB);
  k_sattn5<<<dim3(NBS, HEADS, 7), blk, 0, stream>>>(QB, KB, VB, OBuf);
  // 4) fused spatial proj+LN + temporal QKV -> A (f32), Q2/K2/V2 (bf16)
  k_sproj_tqkv<<<NR / 32, blk, 0, stream>>>(OBuf, WB + 7 * 4096, bo_s, P, g_s,
                                            be_s, WB + 12288, WB + 16384,
                                            WB + 20480, bq_t, bk_t, bv_t, A, Q2,
                                            K2, V2);
  // 5) temporal attention -> TB
  k_tattn<<<NB * NN, blk, 0, stream>>>(Q2, K2, V2, TB);
  // 6) fused temporal proj + LN_t + LN1 + FFN + final LN -> out
  k_tproj_ffn<<<NR / 32, blk, 0, stream>>>(TB, WB + 8 * 4096, bo_t, A, g_t,
                                           be_t, g1, be1, W1B, b1, W2B, b2, g2,
                                           be2, out);
}